// Round 1
// baseline (548.472 us; speedup 1.0000x reference)
//
#include <hip/hip_runtime.h>

// SinkhornAttention — round 0: correctness-first f32 pipeline.
// Key simplification: einsum('bkshd,bnhl->bnshd', block_k, permutation)
// contracts k and l independently; sum_l softmax == 1, so
// sorted_key[b,n,s,h,d] == sum_k block_k[b,k,s,h,d]  (Wsort/bsort are dead).

constexpr int BB   = 4;
constexpr int LL   = 4096;
constexpr int DD   = 512;
constexpr int HH   = 8;
constexpr int HDIM = 64;
constexpr int BS   = 64;
constexpr int NBLK = 64;
constexpr int MTOT = BB * LL;   // 16384

// ---------------- GEMM + bias: C[M,N] = A[M,K] @ W[K,N] + bias[N] ------------
// BM=BN=128, BK=16, 256 threads, 8x8 per thread in 4 quads of 4x4.
__global__ __launch_bounds__(256) void gemm_bias(
    const float* __restrict__ A, const float* __restrict__ W,
    const float* __restrict__ bias, float* __restrict__ C,
    int M, int N, int K)
{
  constexpr int BM = 128, BN = 128, BK = 16;
  __shared__ __align__(16) float Ast[BK][BM + 4];  // A^T tile: [k][m]
  __shared__ __align__(16) float Bs[BK][BN + 4];   // B tile:   [k][n]
  const int tid = threadIdx.x;
  const int tx  = tid & 15;   // column group 0..15
  const int ty  = tid >> 4;   // row group    0..15
  const int brow = blockIdx.y * BM;
  const int bcol = blockIdx.x * BN;

  float acc[2][2][4][4];
  #pragma unroll
  for (int qa = 0; qa < 2; ++qa)
    #pragma unroll
    for (int qb = 0; qb < 2; ++qb)
      #pragma unroll
      for (int i = 0; i < 4; ++i)
        #pragma unroll
        for (int j = 0; j < 4; ++j) acc[qa][qb][i][j] = 0.f;

  for (int k0 = 0; k0 < K; k0 += BK) {
    // A tile: 128x16 = 512 float4, 2 per thread; store transposed.
    #pragma unroll
    for (int it = 0; it < 2; ++it) {
      int idx = tid + it * 256;
      int m   = idx >> 2;
      int kq  = (idx & 3) << 2;
      float4 v = *reinterpret_cast<const float4*>(&A[(size_t)(brow + m) * K + k0 + kq]);
      Ast[kq + 0][m] = v.x;
      Ast[kq + 1][m] = v.y;
      Ast[kq + 2][m] = v.z;
      Ast[kq + 3][m] = v.w;
    }
    // B tile: 16x128 = 512 float4, coalesced rows.
    #pragma unroll
    for (int it = 0; it < 2; ++it) {
      int idx = tid + it * 256;
      int kr  = idx >> 5;
      int nq  = (idx & 31) << 2;
      *reinterpret_cast<float4*>(&Bs[kr][nq]) =
          *reinterpret_cast<const float4*>(&W[(size_t)(k0 + kr) * N + bcol + nq]);
    }
    __syncthreads();
    #pragma unroll
    for (int kk = 0; kk < BK; ++kk) {
      float4 a0 = *reinterpret_cast<const float4*>(&Ast[kk][ty * 4]);
      float4 a1 = *reinterpret_cast<const float4*>(&Ast[kk][ty * 4 + 64]);
      float4 b0 = *reinterpret_cast<const float4*>(&Bs[kk][tx * 4]);
      float4 b1 = *reinterpret_cast<const float4*>(&Bs[kk][tx * 4 + 64]);
      float av[2][4] = {{a0.x, a0.y, a0.z, a0.w}, {a1.x, a1.y, a1.z, a1.w}};
      float bv[2][4] = {{b0.x, b0.y, b0.z, b0.w}, {b1.x, b1.y, b1.z, b1.w}};
      #pragma unroll
      for (int qa = 0; qa < 2; ++qa)
        #pragma unroll
        for (int qb = 0; qb < 2; ++qb)
          #pragma unroll
          for (int i = 0; i < 4; ++i)
            #pragma unroll
            for (int j = 0; j < 4; ++j)
              acc[qa][qb][i][j] += av[qa][i] * bv[qb][j];
    }
    __syncthreads();
  }

  #pragma unroll
  for (int qa = 0; qa < 2; ++qa) {
    #pragma unroll
    for (int i = 0; i < 4; ++i) {
      const int row = brow + ty * 4 + qa * 64 + i;
      #pragma unroll
      for (int qb = 0; qb < 2; ++qb) {
        const int colb = bcol + tx * 4 + qb * 64;
        float4 bb = *reinterpret_cast<const float4*>(&bias[colb]);
        float4 o;
        o.x = acc[qa][qb][i][0] + bb.x;
        o.y = acc[qa][qb][i][1] + bb.y;
        o.z = acc[qa][qb][i][2] + bb.z;
        o.w = acc[qa][qb][i][3] + bb.w;
        *reinterpret_cast<float4*>(&C[(size_t)row * N + colb]) = o;
      }
    }
  }
}

// ---------------- block-sum of K and V over the 64 blocks --------------------
// Ksum[b,s,c] = sum_kb K[b, kb*64+s, c]   (c = h*64+d), same for V.
__global__ __launch_bounds__(256) void sumkv_kernel(
    const float* __restrict__ K, const float* __restrict__ V,
    float* __restrict__ Ks, float* __restrict__ Vs)
{
  const int idx = blockIdx.x * 256 + threadIdx.x;   // 0 .. 4*64*512-1
  const int c = idx & 511;
  const int s = (idx >> 9) & 63;
  const int b = idx >> 15;
  const size_t base = ((size_t)b * LL + s) * DD + c;
  float ks = 0.f, vs = 0.f;
  #pragma unroll 4
  for (int kb = 0; kb < NBLK; ++kb) {
    const size_t off = base + (size_t)kb * BS * DD;
    ks += K[off];
    vs += V[off];
  }
  Ks[idx] = ks;
  Vs[idx] = vs;
}

// ---------------- fused two-pass block attention -----------------------------
// One block per (b, n, h).  256 threads: 64 rows x 4 parts.
// Pass 1: K/V = the block's own K,V tile.  Pass 2: K/V = Ksum/Vsum tile.
__global__ __launch_bounds__(256) void attn_kernel(
    const float* __restrict__ Q, const float* __restrict__ Kg,
    const float* __restrict__ Vg, const float* __restrict__ Ks,
    const float* __restrict__ Vs, float* __restrict__ X)
{
  const int n = blockIdx.x, h = blockIdx.y, b = blockIdx.z;
  __shared__ __align__(16) float sS[64][68];   // Q staging, then scores/weights
  __shared__ __align__(16) float sK[64][68];
  __shared__ __align__(16) float sV[64][68];
  const int tid  = threadIdx.x;
  const int row  = tid >> 2;
  const int part = tid & 3;
  const float scale = 0.125f;   // 1/sqrt(64)

  const size_t tbase = ((size_t)(b * LL + n * BS)) * DD + h * HDIM;
  const size_t sbase = ((size_t)(b * BS)) * DD + h * HDIM;   // Ksum rows

  // stage Q (into sS), K, V  (64x64 f32 tiles, coalesced float4)
  #pragma unroll
  for (int it = 0; it < 4; ++it) {
    int idx = tid + it * 256;          // 1024 float4 slots
    int r   = idx >> 4;
    int dq  = (idx & 15) << 2;
    size_t g = tbase + (size_t)r * DD + dq;
    *reinterpret_cast<float4*>(&sS[r][dq]) = *reinterpret_cast<const float4*>(&Q[g]);
    *reinterpret_cast<float4*>(&sK[r][dq]) = *reinterpret_cast<const float4*>(&Kg[g]);
    *reinterpret_cast<float4*>(&sV[r][dq]) = *reinterpret_cast<const float4*>(&Vg[g]);
  }
  __syncthreads();

  // each thread keeps its row's full q in registers
  float qr[64];
  #pragma unroll
  for (int dq = 0; dq < 16; ++dq) {
    float4 v = *reinterpret_cast<const float4*>(&sS[row][dq << 2]);
    qr[dq * 4 + 0] = v.x; qr[dq * 4 + 1] = v.y;
    qr[dq * 4 + 2] = v.z; qr[dq * 4 + 3] = v.w;
  }
  __syncthreads();   // all qr reads done before sS is reused for scores

  float acc[4][4];
  #pragma unroll
  for (int g = 0; g < 4; ++g)
    #pragma unroll
    for (int c = 0; c < 4; ++c) acc[g][c] = 0.f;

  for (int pass = 0; pass < 2; ++pass) {
    // ---- scores: this thread owns j = part + 4*jj (interleaved across parts)
    float sc[16];
    #pragma unroll
    for (int jj = 0; jj < 16; ++jj) {
      const int j = part + (jj << 2);
      float s = 0.f;
      #pragma unroll
      for (int dq = 0; dq < 16; ++dq) {
        float4 kv = *reinterpret_cast<const float4*>(&sK[j][dq << 2]);
        s += qr[dq * 4 + 0] * kv.x + qr[dq * 4 + 1] * kv.y +
             qr[dq * 4 + 2] * kv.z + qr[dq * 4 + 3] * kv.w;
      }
      sc[jj] = s * scale;
    }
    #pragma unroll
    for (int jj = 0; jj < 16; ++jj) sS[row][part + (jj << 2)] = sc[jj];
    __syncthreads();

    // ---- row softmax (each of the 4 row-threads redundantly reduces the row)
    float m = -1e30f;
    #pragma unroll
    for (int j2 = 0; j2 < 64; ++j2) m = fmaxf(m, sS[row][j2]);
    float sum = 0.f;
    #pragma unroll
    for (int j2 = 0; j2 < 64; ++j2) sum += __expf(sS[row][j2] - m);
    const float inv = 1.0f / sum;
    float w[16];
    #pragma unroll
    for (int jj = 0; jj < 16; ++jj) w[jj] = __expf(sc[jj] - m) * inv;
    __syncthreads();   // all raw-score reads done before overwriting with w
    #pragma unroll
    for (int jj = 0; jj < 16; ++jj) sS[row][part + (jj << 2)] = w[jj];
    __syncthreads();

    // ---- PV: this thread owns d = part*4 + g*16 + c
    #pragma unroll
    for (int j = 0; j < 64; ++j) {
      const float wv = sS[row][j];
      #pragma unroll
      for (int g = 0; g < 4; ++g) {
        float4 vv = *reinterpret_cast<const float4*>(&sV[j][part * 4 + g * 16]);
        acc[g][0] += wv * vv.x;
        acc[g][1] += wv * vv.y;
        acc[g][2] += wv * vv.z;
        acc[g][3] += wv * vv.w;
      }
    }

    if (pass == 0) {
      __syncthreads();   // PV reads of sK/sV/sS done
      #pragma unroll
      for (int it = 0; it < 4; ++it) {
        int idx = tid + it * 256;
        int r   = idx >> 4;
        int dq  = (idx & 15) << 2;
        size_t g = sbase + (size_t)r * DD + dq;
        *reinterpret_cast<float4*>(&sK[r][dq]) = *reinterpret_cast<const float4*>(&Ks[g]);
        *reinterpret_cast<float4*>(&sV[r][dq]) = *reinterpret_cast<const float4*>(&Vs[g]);
      }
      __syncthreads();
    }
  }

  // ---- write x = attn1 + attn2, layout (B, L, H*HD)
  #pragma unroll
  for (int g = 0; g < 4; ++g) {
    float4 o = {acc[g][0], acc[g][1], acc[g][2], acc[g][3]};
    *reinterpret_cast<float4*>(&X[tbase + (size_t)row * DD + part * 4 + g * 16]) = o;
  }
}

// ---------------- launcher ---------------------------------------------------
extern "C" void kernel_launch(void* const* d_in, const int* in_sizes, int n_in,
                              void* d_out, int out_size, void* d_ws, size_t ws_size,
                              hipStream_t stream) {
  const float* x_in = (const float*)d_in[0];
  const float* Wq   = (const float*)d_in[1];
  const float* bq   = (const float*)d_in[2];
  const float* Wk   = (const float*)d_in[3];
  const float* bk   = (const float*)d_in[4];
  const float* Wv   = (const float*)d_in[5];
  const float* bv   = (const float*)d_in[6];
  // d_in[7] = Wsort, d_in[8] = bsort: provably unused (softmax rows sum to 1)
  const float* Wout = (const float*)d_in[9];
  const float* bout = (const float*)d_in[10];
  float* out = (float*)d_out;

  const size_t NQKV = (size_t)MTOT * DD;          // 8,388,608 floats
  float* Q  = (float*)d_ws;
  float* K  = Q  + NQKV;
  float* V  = K  + NQKV;
  float* X  = V  + NQKV;
  float* Ks = X  + NQKV;
  float* Vs = Ks + (size_t)BB * BS * DD;          // needs ~135 MB total

  dim3 gg(DD / 128, MTOT / 128);                  // (4, 128)
  gemm_bias<<<gg, 256, 0, stream>>>(x_in, Wq, bq, Q, MTOT, DD, DD);
  gemm_bias<<<gg, 256, 0, stream>>>(x_in, Wk, bk, K, MTOT, DD, DD);
  gemm_bias<<<gg, 256, 0, stream>>>(x_in, Wv, bv, V, MTOT, DD, DD);

  sumkv_kernel<<<(BB * BS * DD) / 256, 256, 0, stream>>>(K, V, Ks, Vs);

  attn_kernel<<<dim3(NBLK, HH, BB), 256, 0, stream>>>(Q, K, V, Ks, Vs, X);

  gemm_bias<<<gg, 256, 0, stream>>>(X, Wout, bout, out, MTOT, DD, DD);
}

// Round 2
// 256.280 us; speedup vs baseline: 2.1401x; 2.1401x over previous
//
#include <hip/hip_runtime.h>

// SinkhornAttention — round 2: bf16 MFMA GEMMs (QKV fused + out), f32 attn.
// Math simplification (round 0, verified): sorted_key/value reduce to the
// block-sum of K/V; Wsort/bsort are dead.

constexpr int BB   = 4;
constexpr int LL   = 4096;
constexpr int DD   = 512;
constexpr int HH   = 8;
constexpr int HDIM = 64;
constexpr int BS   = 64;
constexpr int NBLK = 64;
constexpr int MTOT = BB * LL;   // 16384

using f32x4  = __attribute__((ext_vector_type(4))) float;
typedef __attribute__((ext_vector_type(8))) __bf16 bf16x8;

static __device__ __forceinline__ ushort f2bf(float f) {
  uint u = __float_as_uint(f);
  uint r = (u + 0x7fffu + ((u >> 16) & 1u)) >> 16;   // RNE
  return (ushort)r;
}
static __device__ __forceinline__ float bflo(uint u) { return __uint_as_float(u << 16); }
static __device__ __forceinline__ float bfhi(uint u) { return __uint_as_float(u & 0xffff0000u); }

#define GLOBAL_AS(p) ((const __attribute__((address_space(1))) void*)(p))
#define LDS_AS(p)    ((__attribute__((address_space(3))) void*)(p))

// ---------------- f32 -> bf16 straight cast (4 elems/thread) -----------------
__global__ __launch_bounds__(256) void f32_to_bf16_vec(
    const float* __restrict__ src, ushort* __restrict__ dst)
{
  const int i = blockIdx.x * 256 + threadIdx.x;
  float4 v = reinterpret_cast<const float4*>(src)[i];
  ushort4 o;
  o.x = f2bf(v.x); o.y = f2bf(v.y); o.z = f2bf(v.z); o.w = f2bf(v.w);
  reinterpret_cast<ushort4*>(dst)[i] = o;
}

// ---------------- transpose + cast: src f32 [R][C] -> dst bf16 [C][R] --------
__global__ __launch_bounds__(256) void transpose_cast(
    const float* __restrict__ src, ushort* __restrict__ dst, int R, int C)
{
  __shared__ float tile[32][33];
  const int tx = threadIdx.x & 31, ty = threadIdx.x >> 5;   // 32 x 8
  const int r0 = blockIdx.y * 32, c0 = blockIdx.x * 32;
  #pragma unroll
  for (int q = 0; q < 4; ++q)
    tile[ty + 8 * q][tx] = src[(size_t)(r0 + ty + 8 * q) * C + c0 + tx];
  __syncthreads();
  #pragma unroll
  for (int q = 0; q < 4; ++q)
    dst[(size_t)(c0 + ty + 8 * q) * R + r0 + tx] = f2bf(tile[tx][ty + 8 * q]);
}

// ---------------- concat Q/K/V biases into one f32[1536] ---------------------
__global__ void concat_bias(const float* __restrict__ bq, const float* __restrict__ bk,
                            const float* __restrict__ bv, float* __restrict__ o)
{
  const int t = threadIdx.x;   // 512
  o[t] = bq[t]; o[512 + t] = bk[t]; o[1024 + t] = bv[t];
}

// ---------------- bf16 MFMA GEMM: C[M,N] = A[M,K] @ Bt[N,K]^T + bias ---------
// 128x128 tile, BK=32, 4 waves (2x2 of 64x64), global_load_lds width-16.
// MODE 0: N=1536, scatter bf16 into Q/K/V (n>>9 selects). MODE 1: f32 out.
template<int MODE>
__global__ __launch_bounds__(256) void gemm_mfma(
    const ushort* __restrict__ A, const ushort* __restrict__ Bt,
    const float* __restrict__ bias,
    ushort* __restrict__ Cq, ushort* __restrict__ Ck, ushort* __restrict__ Cv,
    float* __restrict__ Cf, int M, int N, int K)
{
  __shared__ __align__(16) ushort sA[128 * 32];
  __shared__ __align__(16) ushort sB[128 * 32];
  const int tid  = threadIdx.x;
  const int lane = tid & 63;
  const int w    = tid >> 6;
  const int wr   = w >> 1, wc = w & 1;
  const int brow = blockIdx.y * 128;
  const int bcol = blockIdx.x * 128;
  const int lr   = lane & 15;     // row/col within fragment
  const int kq   = lane >> 4;     // k-quad (8 elems each)

  f32x4 acc[4][4];
  #pragma unroll
  for (int mi = 0; mi < 4; ++mi)
    #pragma unroll
    for (int ni = 0; ni < 4; ++ni)
      acc[mi][ni] = (f32x4){0.f, 0.f, 0.f, 0.f};

  for (int k0 = 0; k0 < K; k0 += 32) {
    #pragma unroll
    for (int it = 0; it < 2; ++it) {
      const int chunk = w + it * 4;          // 0..7, wave-uniform
      const int i     = chunk * 64 + lane;   // 0..511 16B-slots
      const int row   = i >> 2;
      const int c8    = (i & 3) << 3;
      const ushort* srcA = A  + (size_t)(brow + row) * K + k0 + c8;
      const ushort* srcB = Bt + (size_t)(bcol + row) * K + k0 + c8;
      __builtin_amdgcn_global_load_lds(GLOBAL_AS(srcA), LDS_AS(sA + chunk * 512), 16, 0, 0);
      __builtin_amdgcn_global_load_lds(GLOBAL_AS(srcB), LDS_AS(sB + chunk * 512), 16, 0, 0);
    }
    __syncthreads();

    bf16x8 af[4], bfr[4];
    #pragma unroll
    for (int mi = 0; mi < 4; ++mi)
      af[mi] = *reinterpret_cast<const bf16x8*>(sA + (wr * 64 + mi * 16 + lr) * 32 + kq * 8);
    #pragma unroll
    for (int ni = 0; ni < 4; ++ni)
      bfr[ni] = *reinterpret_cast<const bf16x8*>(sB + (wc * 64 + ni * 16 + lr) * 32 + kq * 8);
    #pragma unroll
    for (int mi = 0; mi < 4; ++mi)
      #pragma unroll
      for (int ni = 0; ni < 4; ++ni)
        acc[mi][ni] = __builtin_amdgcn_mfma_f32_16x16x32_bf16(af[mi], bfr[ni], acc[mi][ni], 0, 0, 0);
    __syncthreads();
  }

  // epilogue: C/D layout col=lane&15, row=(lane>>4)*4+reg  [verified m89/m91]
  #pragma unroll
  for (int mi = 0; mi < 4; ++mi) {
    #pragma unroll
    for (int ni = 0; ni < 4; ++ni) {
      const int col = bcol + wc * 64 + ni * 16 + lr;
      const float bb = bias[col];
      if (MODE == 0) {
        const int which = col >> 9;
        const int nn    = col & 511;
        ushort* dst = (which == 0) ? Cq : ((which == 1) ? Ck : Cv);
        #pragma unroll
        for (int r = 0; r < 4; ++r) {
          const int row = brow + wr * 64 + mi * 16 + kq * 4 + r;
          dst[(size_t)row * DD + nn] = f2bf(acc[mi][ni][r] + bb);
        }
      } else {
        #pragma unroll
        for (int r = 0; r < 4; ++r) {
          const int row = brow + wr * 64 + mi * 16 + kq * 4 + r;
          Cf[(size_t)row * N + col] = acc[mi][ni][r] + bb;
        }
      }
    }
  }
}

// ---------------- block-sum of K,V (bf16 in, f32 atomic out) -----------------
// grid (64, 8): blockIdx.y owns 8 of the 64 kb blocks; atomicAdd merge.
__global__ __launch_bounds__(256) void sumkv_kernel(
    const ushort* __restrict__ K, const ushort* __restrict__ V,
    float* __restrict__ Ks, float* __restrict__ Vs)
{
  const int idx = blockIdx.x * 256 + threadIdx.x;   // 16384 c8-slots
  const int kb0 = blockIdx.y * 8;
  const int c8  = (idx & 63) << 3;
  const int s   = (idx >> 6) & 63;
  const int b   = idx >> 12;
  const size_t base = ((size_t)b * LL + s) * DD + c8;
  float ak[8] = {0, 0, 0, 0, 0, 0, 0, 0}, av[8] = {0, 0, 0, 0, 0, 0, 0, 0};
  #pragma unroll
  for (int kk = 0; kk < 8; ++kk) {
    const size_t off = base + (size_t)(kb0 + kk) * BS * DD;
    uint4 ku = *reinterpret_cast<const uint4*>(K + off);
    uint4 vu = *reinterpret_cast<const uint4*>(V + off);
    ak[0] += bflo(ku.x); ak[1] += bfhi(ku.x); ak[2] += bflo(ku.y); ak[3] += bfhi(ku.y);
    ak[4] += bflo(ku.z); ak[5] += bfhi(ku.z); ak[6] += bflo(ku.w); ak[7] += bfhi(ku.w);
    av[0] += bflo(vu.x); av[1] += bfhi(vu.x); av[2] += bflo(vu.y); av[3] += bfhi(vu.y);
    av[4] += bflo(vu.z); av[5] += bfhi(vu.z); av[6] += bflo(vu.w); av[7] += bfhi(vu.w);
  }
  const size_t o = ((size_t)(b * BS + s)) * DD + c8;
  #pragma unroll
  for (int i = 0; i < 8; ++i) {
    atomicAdd(&Ks[o + i], ak[i]);
    atomicAdd(&Vs[o + i], av[i]);
  }
}

// ---------------- fused two-pass block attention (f32 math, bf16 I/O) --------
__global__ __launch_bounds__(256) void attn_kernel(
    const ushort* __restrict__ Q, const ushort* __restrict__ Kg,
    const ushort* __restrict__ Vg, const float* __restrict__ Ks,
    const float* __restrict__ Vs, ushort* __restrict__ X)
{
  const int n = blockIdx.x, h = blockIdx.y, b = blockIdx.z;
  __shared__ __align__(16) float sS[64][68];
  __shared__ __align__(16) float sK[64][68];
  __shared__ __align__(16) float sV[64][68];
  const int tid  = threadIdx.x;
  const int row  = tid >> 2;
  const int part = tid & 3;
  const float scale = 0.125f;

  const size_t tbase = ((size_t)(b * LL + n * BS)) * DD + h * HDIM;
  const size_t sbase = ((size_t)(b * BS)) * DD + h * HDIM;

  // stage Q->sS, K->sK, V->sV from bf16 (8 elems per 16B load)
  #pragma unroll
  for (int it = 0; it < 2; ++it) {
    const int idx = tid + it * 256;       // 0..511
    const int r   = idx >> 3;
    const int c8  = (idx & 7) << 3;
    const size_t g = tbase + (size_t)r * DD + c8;
    uint4 uq = *reinterpret_cast<const uint4*>(Q  + g);
    uint4 uk = *reinterpret_cast<const uint4*>(Kg + g);
    uint4 uv = *reinterpret_cast<const uint4*>(Vg + g);
    sS[r][c8+0]=bflo(uq.x); sS[r][c8+1]=bfhi(uq.x); sS[r][c8+2]=bflo(uq.y); sS[r][c8+3]=bfhi(uq.y);
    sS[r][c8+4]=bflo(uq.z); sS[r][c8+5]=bfhi(uq.z); sS[r][c8+6]=bflo(uq.w); sS[r][c8+7]=bfhi(uq.w);
    sK[r][c8+0]=bflo(uk.x); sK[r][c8+1]=bfhi(uk.x); sK[r][c8+2]=bflo(uk.y); sK[r][c8+3]=bfhi(uk.y);
    sK[r][c8+4]=bflo(uk.z); sK[r][c8+5]=bfhi(uk.z); sK[r][c8+6]=bflo(uk.w); sK[r][c8+7]=bfhi(uk.w);
    sV[r][c8+0]=bflo(uv.x); sV[r][c8+1]=bfhi(uv.x); sV[r][c8+2]=bflo(uv.y); sV[r][c8+3]=bfhi(uv.y);
    sV[r][c8+4]=bflo(uv.z); sV[r][c8+5]=bfhi(uv.z); sV[r][c8+6]=bflo(uv.w); sV[r][c8+7]=bfhi(uv.w);
  }
  __syncthreads();

  float qr[64];
  #pragma unroll
  for (int dq = 0; dq < 16; ++dq) {
    float4 v = *reinterpret_cast<const float4*>(&sS[row][dq << 2]);
    qr[dq*4+0] = v.x; qr[dq*4+1] = v.y; qr[dq*4+2] = v.z; qr[dq*4+3] = v.w;
  }
  __syncthreads();

  float acc[4][4];
  #pragma unroll
  for (int g = 0; g < 4; ++g)
    #pragma unroll
    for (int c = 0; c < 4; ++c) acc[g][c] = 0.f;

  for (int pass = 0; pass < 2; ++pass) {
    float sc[16];
    #pragma unroll
    for (int jj = 0; jj < 16; ++jj) {
      const int j = part + (jj << 2);
      float s = 0.f;
      #pragma unroll
      for (int dq = 0; dq < 16; ++dq) {
        float4 kv = *reinterpret_cast<const float4*>(&sK[j][dq << 2]);
        s += qr[dq*4+0]*kv.x + qr[dq*4+1]*kv.y + qr[dq*4+2]*kv.z + qr[dq*4+3]*kv.w;
      }
      sc[jj] = s * scale;
    }
    #pragma unroll
    for (int jj = 0; jj < 16; ++jj) sS[row][part + (jj << 2)] = sc[jj];
    __syncthreads();

    float m = -1e30f;
    #pragma unroll
    for (int j2 = 0; j2 < 64; ++j2) m = fmaxf(m, sS[row][j2]);
    float sum = 0.f;
    #pragma unroll
    for (int j2 = 0; j2 < 64; ++j2) sum += __expf(sS[row][j2] - m);
    const float inv = 1.0f / sum;
    float wv[16];
    #pragma unroll
    for (int jj = 0; jj < 16; ++jj) wv[jj] = __expf(sc[jj] - m) * inv;
    __syncthreads();
    #pragma unroll
    for (int jj = 0; jj < 16; ++jj) sS[row][part + (jj << 2)] = wv[jj];
    __syncthreads();

    #pragma unroll
    for (int j = 0; j < 64; ++j) {
      const float wj = sS[row][j];
      #pragma unroll
      for (int g = 0; g < 4; ++g) {
        float4 vv = *reinterpret_cast<const float4*>(&sV[j][part * 4 + g * 16]);
        acc[g][0] += wj * vv.x; acc[g][1] += wj * vv.y;
        acc[g][2] += wj * vv.z; acc[g][3] += wj * vv.w;
      }
    }

    if (pass == 0) {
      __syncthreads();
      #pragma unroll
      for (int it = 0; it < 4; ++it) {
        const int idx = tid + it * 256;
        const int r   = idx >> 4;
        const int dq  = (idx & 15) << 2;
        const size_t g = sbase + (size_t)r * DD + dq;
        *reinterpret_cast<float4*>(&sK[r][dq]) = *reinterpret_cast<const float4*>(Ks + g);
        *reinterpret_cast<float4*>(&sV[r][dq]) = *reinterpret_cast<const float4*>(Vs + g);
      }
      __syncthreads();
    }
  }

  #pragma unroll
  for (int g = 0; g < 4; ++g) {
    ushort4 o;
    o.x = f2bf(acc[g][0]); o.y = f2bf(acc[g][1]);
    o.z = f2bf(acc[g][2]); o.w = f2bf(acc[g][3]);
    *reinterpret_cast<ushort4*>(X + tbase + (size_t)row * DD + part * 4 + g * 16) = o;
  }
}

// ---------------- launcher ---------------------------------------------------
extern "C" void kernel_launch(void* const* d_in, const int* in_sizes, int n_in,
                              void* d_out, int out_size, void* d_ws, size_t ws_size,
                              hipStream_t stream) {
  const float* x_in = (const float*)d_in[0];
  const float* Wq   = (const float*)d_in[1];
  const float* bq   = (const float*)d_in[2];
  const float* Wk   = (const float*)d_in[3];
  const float* bk   = (const float*)d_in[4];
  const float* Wv   = (const float*)d_in[5];
  const float* bv   = (const float*)d_in[6];
  const float* Wout = (const float*)d_in[9];
  const float* bout = (const float*)d_in[10];
  float* out = (float*)d_out;

  const size_t NTOK = (size_t)MTOT * DD;          // 8,388,608 elems
  char* ws = (char*)d_ws;
  ushort* xb      = (ushort*)ws;            ws += NTOK * 2;
  ushort* Qb      = (ushort*)ws;            ws += NTOK * 2;
  ushort* Kb      = (ushort*)ws;            ws += NTOK * 2;
  ushort* Vb      = (ushort*)ws;            ws += NTOK * 2;
  ushort* Xb      = (ushort*)ws;            ws += NTOK * 2;
  ushort* Wqkv_t  = (ushort*)ws;            ws += (size_t)1536 * 512 * 2;
  ushort* Wout_t  = (ushort*)ws;            ws += (size_t)512 * 512 * 2;
  float*  bias_qkv= (float*)ws;             ws += 2048 * 4;
  float*  Ksum    = (float*)ws;             ws += (size_t)BB * BS * DD * 4;
  float*  Vsum    = (float*)ws;             ws += (size_t)BB * BS * DD * 4;

  f32_to_bf16_vec<<<NTOK / 4 / 256, 256, 0, stream>>>(x_in, xb);
  dim3 tg(16, 16);
  transpose_cast<<<tg, 256, 0, stream>>>(Wq,   Wqkv_t,               512, 512);
  transpose_cast<<<tg, 256, 0, stream>>>(Wk,   Wqkv_t + 512 * 512,   512, 512);
  transpose_cast<<<tg, 256, 0, stream>>>(Wv,   Wqkv_t + 1024 * 512,  512, 512);
  transpose_cast<<<tg, 256, 0, stream>>>(Wout, Wout_t,               512, 512);
  concat_bias<<<1, 512, 0, stream>>>(bq, bk, bv, bias_qkv);
  hipMemsetAsync(Ksum, 0, (size_t)BB * BS * DD * 4 * 2, stream);

  gemm_mfma<0><<<dim3(1536 / 128, MTOT / 128), 256, 0, stream>>>(
      xb, Wqkv_t, bias_qkv, Qb, Kb, Vb, nullptr, MTOT, 1536, 512);

  sumkv_kernel<<<dim3(64, 8), 256, 0, stream>>>(Kb, Vb, Ksum, Vsum);

  attn_kernel<<<dim3(NBLK, HH, BB), 256, 0, stream>>>(Qb, Kb, Vb, Ksum, Vsum, Xb);

  gemm_mfma<1><<<dim3(512 / 128, MTOT / 128), 256, 0, stream>>>(
      Xb, Wout_t, bout, nullptr, nullptr, nullptr, out, MTOT, 512, 512);
}

// Round 3
// 182.879 us; speedup vs baseline: 2.9991x; 1.4014x over previous
//
#include <hip/hip_runtime.h>

// SinkhornAttention — round 3: MFMA attention (swapped QK^T, transposed-V LDS,
// XOR-swizzled tiles, Ksum hi/lo split for pass-2 precision).
// Math simplification (round 0, verified): sorted_key/value reduce to the
// block-sum of K/V; Wsort/bsort are dead.

constexpr int BB   = 4;
constexpr int LL   = 4096;
constexpr int DD   = 512;
constexpr int HH   = 8;
constexpr int HDIM = 64;
constexpr int BS   = 64;
constexpr int NBLK = 64;
constexpr int MTOT = BB * LL;   // 16384

using f32x4  = __attribute__((ext_vector_type(4))) float;
typedef __attribute__((ext_vector_type(8))) __bf16 bf16x8;

static __device__ __forceinline__ ushort f2bf(float f) {
  uint u = __float_as_uint(f);
  uint r = (u + 0x7fffu + ((u >> 16) & 1u)) >> 16;   // RNE
  return (ushort)r;
}
static __device__ __forceinline__ float bf2f(ushort u) { return __uint_as_float((uint)u << 16); }
static __device__ __forceinline__ float bflo(uint u) { return __uint_as_float(u << 16); }
static __device__ __forceinline__ float bfhi(uint u) { return __uint_as_float(u & 0xffff0000u); }

// swizzled ushort index into a 64x64 bf16 tile (row stride 128 B):
// byte = row*128 + (colbytes ^ ((row&7)<<4))  -> 2-way (free) read conflicts
static __device__ __forceinline__ int swb(int row, int cb) {
  return (row << 6) + ((cb ^ ((row & 7) << 4)) >> 1);
}

#define GLOBAL_AS(p) ((const __attribute__((address_space(1))) void*)(p))
#define LDS_AS(p)    ((__attribute__((address_space(3))) void*)(p))

// ---------------- f32 -> bf16 straight cast (4 elems/thread) -----------------
__global__ __launch_bounds__(256) void f32_to_bf16_vec(
    const float* __restrict__ src, ushort* __restrict__ dst)
{
  const int i = blockIdx.x * 256 + threadIdx.x;
  float4 v = reinterpret_cast<const float4*>(src)[i];
  ushort4 o;
  o.x = f2bf(v.x); o.y = f2bf(v.y); o.z = f2bf(v.z); o.w = f2bf(v.w);
  reinterpret_cast<ushort4*>(dst)[i] = o;
}

// ---------------- transpose + cast: src f32 [R][C] -> dst bf16 [C][R] --------
__global__ __launch_bounds__(256) void transpose_cast(
    const float* __restrict__ src, ushort* __restrict__ dst, int R, int C)
{
  __shared__ float tile[32][33];
  const int tx = threadIdx.x & 31, ty = threadIdx.x >> 5;   // 32 x 8
  const int r0 = blockIdx.y * 32, c0 = blockIdx.x * 32;
  #pragma unroll
  for (int q = 0; q < 4; ++q)
    tile[ty + 8 * q][tx] = src[(size_t)(r0 + ty + 8 * q) * C + c0 + tx];
  __syncthreads();
  #pragma unroll
  for (int q = 0; q < 4; ++q)
    dst[(size_t)(c0 + ty + 8 * q) * R + r0 + tx] = f2bf(tile[tx][ty + 8 * q]);
}

// ---------------- concat Q/K/V biases into one f32[1536] ---------------------
__global__ void concat_bias(const float* __restrict__ bq, const float* __restrict__ bk,
                            const float* __restrict__ bv, float* __restrict__ o)
{
  const int t = threadIdx.x;   // 512
  o[t] = bq[t]; o[512 + t] = bk[t]; o[1024 + t] = bv[t];
}

// ---------------- bf16 MFMA GEMM: C[M,N] = A[M,K] @ Bt[N,K]^T + bias ---------
template<int MODE>
__global__ __launch_bounds__(256) void gemm_mfma(
    const ushort* __restrict__ A, const ushort* __restrict__ Bt,
    const float* __restrict__ bias,
    ushort* __restrict__ Cq, ushort* __restrict__ Ck, ushort* __restrict__ Cv,
    float* __restrict__ Cf, int M, int N, int K)
{
  __shared__ __align__(16) ushort sA[128 * 32];
  __shared__ __align__(16) ushort sB[128 * 32];
  const int tid  = threadIdx.x;
  const int lane = tid & 63;
  const int w    = tid >> 6;
  const int wr   = w >> 1, wc = w & 1;
  const int brow = blockIdx.y * 128;
  const int bcol = blockIdx.x * 128;
  const int lr   = lane & 15;
  const int kq   = lane >> 4;

  f32x4 acc[4][4];
  #pragma unroll
  for (int mi = 0; mi < 4; ++mi)
    #pragma unroll
    for (int ni = 0; ni < 4; ++ni)
      acc[mi][ni] = (f32x4){0.f, 0.f, 0.f, 0.f};

  for (int k0 = 0; k0 < K; k0 += 32) {
    #pragma unroll
    for (int it = 0; it < 2; ++it) {
      const int chunk = w + it * 4;
      const int i     = chunk * 64 + lane;
      const int row   = i >> 2;
      const int c8    = (i & 3) << 3;
      const ushort* srcA = A  + (size_t)(brow + row) * K + k0 + c8;
      const ushort* srcB = Bt + (size_t)(bcol + row) * K + k0 + c8;
      __builtin_amdgcn_global_load_lds(GLOBAL_AS(srcA), LDS_AS(sA + chunk * 512), 16, 0, 0);
      __builtin_amdgcn_global_load_lds(GLOBAL_AS(srcB), LDS_AS(sB + chunk * 512), 16, 0, 0);
    }
    __syncthreads();

    bf16x8 af[4], bfr[4];
    #pragma unroll
    for (int mi = 0; mi < 4; ++mi)
      af[mi] = *reinterpret_cast<const bf16x8*>(sA + (wr * 64 + mi * 16 + lr) * 32 + kq * 8);
    #pragma unroll
    for (int ni = 0; ni < 4; ++ni)
      bfr[ni] = *reinterpret_cast<const bf16x8*>(sB + (wc * 64 + ni * 16 + lr) * 32 + kq * 8);
    #pragma unroll
    for (int mi = 0; mi < 4; ++mi)
      #pragma unroll
      for (int ni = 0; ni < 4; ++ni)
        acc[mi][ni] = __builtin_amdgcn_mfma_f32_16x16x32_bf16(af[mi], bfr[ni], acc[mi][ni], 0, 0, 0);
    __syncthreads();
  }

  #pragma unroll
  for (int mi = 0; mi < 4; ++mi) {
    #pragma unroll
    for (int ni = 0; ni < 4; ++ni) {
      const int col = bcol + wc * 64 + ni * 16 + lr;
      const float bb = bias[col];
      if (MODE == 0) {
        const int which = col >> 9;
        const int nn    = col & 511;
        ushort* dst = (which == 0) ? Cq : ((which == 1) ? Ck : Cv);
        #pragma unroll
        for (int r = 0; r < 4; ++r) {
          const int row = brow + wr * 64 + mi * 16 + kq * 4 + r;
          dst[(size_t)row * DD + nn] = f2bf(acc[mi][ni][r] + bb);
        }
      } else {
        #pragma unroll
        for (int r = 0; r < 4; ++r) {
          const int row = brow + wr * 64 + mi * 16 + kq * 4 + r;
          Cf[(size_t)row * N + col] = acc[mi][ni][r] + bb;
        }
      }
    }
  }
}

// ---------------- block-sum of K,V (bf16 in, f32 atomic out) -----------------
__global__ __launch_bounds__(256) void sumkv_kernel(
    const ushort* __restrict__ K, const ushort* __restrict__ V,
    float* __restrict__ Ks, float* __restrict__ Vs)
{
  const int idx = blockIdx.x * 256 + threadIdx.x;   // 16384 c8-slots
  const int kb0 = blockIdx.y * 8;
  const int c8  = (idx & 63) << 3;
  const int s   = (idx >> 6) & 63;
  const int b   = idx >> 12;
  const size_t base = ((size_t)b * LL + s) * DD + c8;
  float ak[8] = {0, 0, 0, 0, 0, 0, 0, 0}, av[8] = {0, 0, 0, 0, 0, 0, 0, 0};
  #pragma unroll
  for (int kk = 0; kk < 8; ++kk) {
    const size_t off = base + (size_t)(kb0 + kk) * BS * DD;
    uint4 ku = *reinterpret_cast<const uint4*>(K + off);
    uint4 vu = *reinterpret_cast<const uint4*>(V + off);
    ak[0] += bflo(ku.x); ak[1] += bfhi(ku.x); ak[2] += bflo(ku.y); ak[3] += bfhi(ku.y);
    ak[4] += bflo(ku.z); ak[5] += bfhi(ku.z); ak[6] += bflo(ku.w); ak[7] += bfhi(ku.w);
    av[0] += bflo(vu.x); av[1] += bfhi(vu.x); av[2] += bflo(vu.y); av[3] += bfhi(vu.y);
    av[4] += bflo(vu.z); av[5] += bfhi(vu.z); av[6] += bflo(vu.w); av[7] += bfhi(vu.w);
  }
  const size_t o = ((size_t)(b * BS + s)) * DD + c8;
  #pragma unroll
  for (int i = 0; i < 8; ++i) {
    atomicAdd(&Ks[o + i], ak[i]);
    atomicAdd(&Vs[o + i], av[i]);
  }
}

// ---------------- finalize: Ksum f32 -> (khi, klo) bf16, Vsum -> bf16 --------
__global__ __launch_bounds__(256) void finalize_kv(
    const float* __restrict__ Ks, const float* __restrict__ Vs,
    ushort* __restrict__ Khi, ushort* __restrict__ Klo, ushort* __restrict__ Vb)
{
  const int i = blockIdx.x * 256 + threadIdx.x;   // 131072
  const float ks = Ks[i];
  const ushort h = f2bf(ks);
  Khi[i] = h;
  Klo[i] = f2bf(ks - bf2f(h));
  Vb[i]  = f2bf(Vs[i]);
}

// ---------------- MFMA two-pass block attention ------------------------------
// 1 block per (b,n,h); 4 waves x 16 q-rows. Swapped QK^T: S^T = K·Q^T so the
// softmax row lives on 4 lanes (shfl_xor 16/32). P -> bf16 -> LDS; PV with
// V transposed in LDS. Pass 2 uses Khi+Klo (exact Ksum) and Vb.
__global__ __launch_bounds__(256) void attn_mfma(
    const ushort* __restrict__ Q, const ushort* __restrict__ Kg,
    const ushort* __restrict__ Vg, const ushort* __restrict__ Khi,
    const ushort* __restrict__ Klo, const ushort* __restrict__ Vsb,
    ushort* __restrict__ X)
{
  __shared__ __align__(16) ushort sA[64 * 64];   // K, then Khi
  __shared__ __align__(16) ushort sC[64 * 64];   // Klo (pass 2)
  __shared__ __align__(16) ushort sVt[64 * 64];  // V^T, then Vsum^T
  __shared__ __align__(16) ushort sP[64 * 64];   // P (per-wave 16-row slices)
  const int n = blockIdx.x, h = blockIdx.y, b = blockIdx.z;
  const int tid  = threadIdx.x;
  const int lane = tid & 63;
  const int w    = tid >> 6;
  const int lr   = lane & 15, hi4 = lane >> 4;
  const float scale = 0.125f;

  const size_t tbase = ((size_t)(b * LL + n * BS)) * DD + h * HDIM;
  const size_t sbase = ((size_t)(b * BS)) * DD + h * HDIM;

  // ---- issue ALL global loads up front (pass-2 data held in regs thru pass 1)
  uint4 k1[2], v1[2], k2h[2], k2l[2], v2[2];
  int rr[2], cc[2];
  #pragma unroll
  for (int it = 0; it < 2; ++it) {
    const int i  = tid + it * 256;      // 0..511
    const int r  = i >> 3;
    const int c8 = (i & 7) << 3;
    rr[it] = r; cc[it] = c8;
    const size_t g1 = tbase + (size_t)r * DD + c8;
    const size_t g2 = sbase + (size_t)r * DD + c8;
    k1[it]  = *reinterpret_cast<const uint4*>(Kg  + g1);
    v1[it]  = *reinterpret_cast<const uint4*>(Vg  + g1);
    k2h[it] = *reinterpret_cast<const uint4*>(Khi + g2);
    k2l[it] = *reinterpret_cast<const uint4*>(Klo + g2);
    v2[it]  = *reinterpret_cast<const uint4*>(Vsb + g2);
  }
  // Q B-fragments (held in regs for the whole kernel); col q = lane&15
  bf16x8 qf[2];
  #pragma unroll
  for (int ks = 0; ks < 2; ++ks)
    qf[ks] = *reinterpret_cast<const bf16x8*>(
        Q + tbase + (size_t)(w * 16 + lr) * DD + ks * 32 + hi4 * 8);

  // ---- stage pass-1 tiles
  #pragma unroll
  for (int it = 0; it < 2; ++it) {
    *reinterpret_cast<uint4*>(&sA[swb(rr[it], cc[it] << 1)]) = k1[it];
    const uint u[4] = {v1[it].x, v1[it].y, v1[it].z, v1[it].w};
    #pragma unroll
    for (int j = 0; j < 4; ++j) {
      sVt[swb(cc[it] + 2 * j,     rr[it] << 1)] = (ushort)(u[j] & 0xffff);
      sVt[swb(cc[it] + 2 * j + 1, rr[it] << 1)] = (ushort)(u[j] >> 16);
    }
  }
  __syncthreads();

  f32x4 xacc[4];
  #pragma unroll
  for (int dt = 0; dt < 4; ++dt) xacc[dt] = (f32x4){0.f, 0.f, 0.f, 0.f};

  // ================= PASS 1 =================
  {
    f32x4 st[4];
    #pragma unroll
    for (int t = 0; t < 4; ++t) st[t] = (f32x4){0.f, 0.f, 0.f, 0.f};
    #pragma unroll
    for (int ks = 0; ks < 2; ++ks) {
      #pragma unroll
      for (int t = 0; t < 4; ++t) {
        bf16x8 kf = *reinterpret_cast<const bf16x8*>(
            &sA[swb(t * 16 + lr, (ks * 32 + hi4 * 8) << 1)]);
        st[t] = __builtin_amdgcn_mfma_f32_16x16x32_bf16(kf, qf[ks], st[t], 0, 0, 0);
      }
    }
    // softmax over keys (row q = lane&15; keys spread over 4 lanes + 16 regs)
    float e[4][4];
    float mx = -1e30f;
    #pragma unroll
    for (int t = 0; t < 4; ++t)
      #pragma unroll
      for (int r = 0; r < 4; ++r) { e[t][r] = st[t][r] * scale; mx = fmaxf(mx, e[t][r]); }
    mx = fmaxf(mx, __shfl_xor(mx, 16));
    mx = fmaxf(mx, __shfl_xor(mx, 32));
    float sum = 0.f;
    #pragma unroll
    for (int t = 0; t < 4; ++t)
      #pragma unroll
      for (int r = 0; r < 4; ++r) { e[t][r] = __expf(e[t][r] - mx); sum += e[t][r]; }
    sum += __shfl_xor(sum, 16);
    sum += __shfl_xor(sum, 32);
    const float inv = 1.0f / sum;
    #pragma unroll
    for (int t = 0; t < 4; ++t) {
      ushort4 p4;
      p4.x = f2bf(e[t][0] * inv); p4.y = f2bf(e[t][1] * inv);
      p4.z = f2bf(e[t][2] * inv); p4.w = f2bf(e[t][3] * inv);
      *reinterpret_cast<ushort4*>(&sP[swb(w * 16 + lr, (t * 16 + hi4 * 4) << 1)]) = p4;
    }
    // PV (same-wave sP producer/consumer: in-order LDS, no barrier needed)
    #pragma unroll
    for (int ks = 0; ks < 2; ++ks) {
      bf16x8 pa = *reinterpret_cast<const bf16x8*>(
          &sP[swb(w * 16 + lr, (ks * 32 + hi4 * 8) << 1)]);
      #pragma unroll
      for (int dt = 0; dt < 4; ++dt) {
        bf16x8 vb = *reinterpret_cast<const bf16x8*>(
            &sVt[swb(dt * 16 + lr, (ks * 32 + hi4 * 8) << 1)]);
        xacc[dt] = __builtin_amdgcn_mfma_f32_16x16x32_bf16(pa, vb, xacc[dt], 0, 0, 0);
      }
    }
  }
  __syncthreads();   // everyone done reading sA/sVt

  // ---- stage pass-2 tiles from held regs
  #pragma unroll
  for (int it = 0; it < 2; ++it) {
    *reinterpret_cast<uint4*>(&sA[swb(rr[it], cc[it] << 1)]) = k2h[it];
    *reinterpret_cast<uint4*>(&sC[swb(rr[it], cc[it] << 1)]) = k2l[it];
    const uint u[4] = {v2[it].x, v2[it].y, v2[it].z, v2[it].w};
    #pragma unroll
    for (int j = 0; j < 4; ++j) {
      sVt[swb(cc[it] + 2 * j,     rr[it] << 1)] = (ushort)(u[j] & 0xffff);
      sVt[swb(cc[it] + 2 * j + 1, rr[it] << 1)] = (ushort)(u[j] >> 16);
    }
  }
  __syncthreads();

  // ================= PASS 2 =================
  {
    f32x4 st[4];
    #pragma unroll
    for (int t = 0; t < 4; ++t) st[t] = (f32x4){0.f, 0.f, 0.f, 0.f};
    #pragma unroll
    for (int ks = 0; ks < 2; ++ks) {
      #pragma unroll
      for (int t = 0; t < 4; ++t) {
        bf16x8 kh = *reinterpret_cast<const bf16x8*>(
            &sA[swb(t * 16 + lr, (ks * 32 + hi4 * 8) << 1)]);
        st[t] = __builtin_amdgcn_mfma_f32_16x16x32_bf16(kh, qf[ks], st[t], 0, 0, 0);
        bf16x8 kl = *reinterpret_cast<const bf16x8*>(
            &sC[swb(t * 16 + lr, (ks * 32 + hi4 * 8) << 1)]);
        st[t] = __builtin_amdgcn_mfma_f32_16x16x32_bf16(kl, qf[ks], st[t], 0, 0, 0);
      }
    }
    float e[4][4];
    float mx = -1e30f;
    #pragma unroll
    for (int t = 0; t < 4; ++t)
      #pragma unroll
      for (int r = 0; r < 4; ++r) { e[t][r] = st[t][r] * scale; mx = fmaxf(mx, e[t][r]); }
    mx = fmaxf(mx, __shfl_xor(mx, 16));
    mx = fmaxf(mx, __shfl_xor(mx, 32));
    float sum = 0.f;
    #pragma unroll
    for (int t = 0; t < 4; ++t)
      #pragma unroll
      for (int r = 0; r < 4; ++r) { e[t][r] = __expf(e[t][r] - mx); sum += e[t][r]; }
    sum += __shfl_xor(sum, 16);
    sum += __shfl_xor(sum, 32);
    const float inv = 1.0f / sum;
    #pragma unroll
    for (int t = 0; t < 4; ++t) {
      ushort4 p4;
      p4.x = f2bf(e[t][0] * inv); p4.y = f2bf(e[t][1] * inv);
      p4.z = f2bf(e[t][2] * inv); p4.w = f2bf(e[t][3] * inv);
      *reinterpret_cast<ushort4*>(&sP[swb(w * 16 + lr, (t * 16 + hi4 * 4) << 1)]) = p4;
    }
    #pragma unroll
    for (int ks = 0; ks < 2; ++ks) {
      bf16x8 pa = *reinterpret_cast<const bf16x8*>(
          &sP[swb(w * 16 + lr, (ks * 32 + hi4 * 8) << 1)]);
      #pragma unroll
      for (int dt = 0; dt < 4; ++dt) {
        bf16x8 vb = *reinterpret_cast<const bf16x8*>(
            &sVt[swb(dt * 16 + lr, (ks * 32 + hi4 * 8) << 1)]);
        xacc[dt] = __builtin_amdgcn_mfma_f32_16x16x32_bf16(pa, vb, xacc[dt], 0, 0, 0);
      }
    }
  }

  // ---- write x = attn1 + attn2 (C/D layout: col=lane&15, row=hi4*4+r)
  #pragma unroll
  for (int dt = 0; dt < 4; ++dt)
    #pragma unroll
    for (int r = 0; r < 4; ++r)
      X[tbase + (size_t)(w * 16 + hi4 * 4 + r) * DD + dt * 16 + lr] = f2bf(xacc[dt][r]);
}

// ---------------- launcher ---------------------------------------------------
extern "C" void kernel_launch(void* const* d_in, const int* in_sizes, int n_in,
                              void* d_out, int out_size, void* d_ws, size_t ws_size,
                              hipStream_t stream) {
  const float* x_in = (const float*)d_in[0];
  const float* Wq   = (const float*)d_in[1];
  const float* bq   = (const float*)d_in[2];
  const float* Wk   = (const float*)d_in[3];
  const float* bk   = (const float*)d_in[4];
  const float* Wv   = (const float*)d_in[5];
  const float* bv   = (const float*)d_in[6];
  const float* Wout = (const float*)d_in[9];
  const float* bout = (const float*)d_in[10];
  float* out = (float*)d_out;

  const size_t NTOK = (size_t)MTOT * DD;          // 8,388,608 elems
  const size_t NSUM = (size_t)BB * BS * DD;       // 131072 elems
  char* ws = (char*)d_ws;
  ushort* xb      = (ushort*)ws;            ws += NTOK * 2;
  ushort* Qb      = (ushort*)ws;            ws += NTOK * 2;
  ushort* Kb      = (ushort*)ws;            ws += NTOK * 2;
  ushort* Vb      = (ushort*)ws;            ws += NTOK * 2;
  ushort* Xb      = (ushort*)ws;            ws += NTOK * 2;
  ushort* Wqkv_t  = (ushort*)ws;            ws += (size_t)1536 * 512 * 2;
  ushort* Wout_t  = (ushort*)ws;            ws += (size_t)512 * 512 * 2;
  float*  bias_qkv= (float*)ws;             ws += 2048 * 4;
  float*  Ksum    = (float*)ws;             ws += NSUM * 4;
  float*  Vsum    = (float*)ws;             ws += NSUM * 4;
  ushort* KhiB    = (ushort*)ws;            ws += NSUM * 2;
  ushort* KloB    = (ushort*)ws;            ws += NSUM * 2;
  ushort* VsB     = (ushort*)ws;            ws += NSUM * 2;

  f32_to_bf16_vec<<<NTOK / 4 / 256, 256, 0, stream>>>(x_in, xb);
  dim3 tg(16, 16);
  transpose_cast<<<tg, 256, 0, stream>>>(Wq,   Wqkv_t,               512, 512);
  transpose_cast<<<tg, 256, 0, stream>>>(Wk,   Wqkv_t + 512 * 512,   512, 512);
  transpose_cast<<<tg, 256, 0, stream>>>(Wv,   Wqkv_t + 1024 * 512,  512, 512);
  transpose_cast<<<tg, 256, 0, stream>>>(Wout, Wout_t,               512, 512);
  concat_bias<<<1, 512, 0, stream>>>(bq, bk, bv, bias_qkv);
  hipMemsetAsync(Ksum, 0, NSUM * 4 * 2, stream);

  gemm_mfma<0><<<dim3(1536 / 128, MTOT / 128), 256, 0, stream>>>(
      xb, Wqkv_t, bias_qkv, Qb, Kb, Vb, nullptr, MTOT, 1536, 512);

  sumkv_kernel<<<dim3(64, 8), 256, 0, stream>>>(Kb, Vb, Ksum, Vsum);
  finalize_kv<<<NSUM / 256, 256, 0, stream>>>(Ksum, Vsum, KhiB, KloB, VsB);

  attn_mfma<<<dim3(NBLK, HH, BB), 256, 0, stream>>>(Qb, Kb, Vb, KhiB, KloB, VsB, Xb);

  gemm_mfma<1><<<dim3(512 / 128, MTOT / 128), 256, 0, stream>>>(
      Xb, Wout_t, bout, nullptr, nullptr, nullptr, out, MTOT, 512, 512);
}

// Round 4
// 124.711 us; speedup vs baseline: 4.3980x; 1.4664x over previous
//
#include <hip/hip_runtime.h>

// SinkhornAttention — round 4: atomic-free fused sumkv (block-per-(b,s),
// in-register kb reduction, direct Khi/Klo/Vb emission).
// Math simplification (round 0, verified): sorted_key/value reduce to the
// block-sum of K/V; Wsort/bsort are dead.

constexpr int BB   = 4;
constexpr int LL   = 4096;
constexpr int DD   = 512;
constexpr int HH   = 8;
constexpr int HDIM = 64;
constexpr int BS   = 64;
constexpr int NBLK = 64;
constexpr int MTOT = BB * LL;   // 16384

using f32x4  = __attribute__((ext_vector_type(4))) float;
typedef __attribute__((ext_vector_type(8))) __bf16 bf16x8;

static __device__ __forceinline__ ushort f2bf(float f) {
  uint u = __float_as_uint(f);
  uint r = (u + 0x7fffu + ((u >> 16) & 1u)) >> 16;   // RNE
  return (ushort)r;
}
static __device__ __forceinline__ float bf2f(ushort u) { return __uint_as_float((uint)u << 16); }
static __device__ __forceinline__ float bflo(uint u) { return __uint_as_float(u << 16); }
static __device__ __forceinline__ float bfhi(uint u) { return __uint_as_float(u & 0xffff0000u); }

// swizzled ushort index into a 64x64 bf16 tile (row stride 128 B)
static __device__ __forceinline__ int swb(int row, int cb) {
  return (row << 6) + ((cb ^ ((row & 7) << 4)) >> 1);
}

#define GLOBAL_AS(p) ((const __attribute__((address_space(1))) void*)(p))
#define LDS_AS(p)    ((__attribute__((address_space(3))) void*)(p))

// ---------------- f32 -> bf16 straight cast (4 elems/thread) -----------------
__global__ __launch_bounds__(256) void f32_to_bf16_vec(
    const float* __restrict__ src, ushort* __restrict__ dst)
{
  const int i = blockIdx.x * 256 + threadIdx.x;
  float4 v = reinterpret_cast<const float4*>(src)[i];
  ushort4 o;
  o.x = f2bf(v.x); o.y = f2bf(v.y); o.z = f2bf(v.z); o.w = f2bf(v.w);
  reinterpret_cast<ushort4*>(dst)[i] = o;
}

// ---------------- transpose + cast: src f32 [R][C] -> dst bf16 [C][R] --------
__global__ __launch_bounds__(256) void transpose_cast(
    const float* __restrict__ src, ushort* __restrict__ dst, int R, int C)
{
  __shared__ float tile[32][33];
  const int tx = threadIdx.x & 31, ty = threadIdx.x >> 5;   // 32 x 8
  const int r0 = blockIdx.y * 32, c0 = blockIdx.x * 32;
  #pragma unroll
  for (int q = 0; q < 4; ++q)
    tile[ty + 8 * q][tx] = src[(size_t)(r0 + ty + 8 * q) * C + c0 + tx];
  __syncthreads();
  #pragma unroll
  for (int q = 0; q < 4; ++q)
    dst[(size_t)(c0 + ty + 8 * q) * R + r0 + tx] = f2bf(tile[tx][ty + 8 * q]);
}

// ---------------- concat Q/K/V biases into one f32[1536] ---------------------
__global__ void concat_bias(const float* __restrict__ bq, const float* __restrict__ bk,
                            const float* __restrict__ bv, float* __restrict__ o)
{
  const int t = threadIdx.x;   // 512
  o[t] = bq[t]; o[512 + t] = bk[t]; o[1024 + t] = bv[t];
}

// ---------------- bf16 MFMA GEMM: C[M,N] = A[M,K] @ Bt[N,K]^T + bias ---------
template<int MODE>
__global__ __launch_bounds__(256) void gemm_mfma(
    const ushort* __restrict__ A, const ushort* __restrict__ Bt,
    const float* __restrict__ bias,
    ushort* __restrict__ Cq, ushort* __restrict__ Ck, ushort* __restrict__ Cv,
    float* __restrict__ Cf, int M, int N, int K)
{
  __shared__ __align__(16) ushort sA[128 * 32];
  __shared__ __align__(16) ushort sB[128 * 32];
  const int tid  = threadIdx.x;
  const int lane = tid & 63;
  const int w    = tid >> 6;
  const int wr   = w >> 1, wc = w & 1;
  const int brow = blockIdx.y * 128;
  const int bcol = blockIdx.x * 128;
  const int lr   = lane & 15;
  const int kq   = lane >> 4;

  f32x4 acc[4][4];
  #pragma unroll
  for (int mi = 0; mi < 4; ++mi)
    #pragma unroll
    for (int ni = 0; ni < 4; ++ni)
      acc[mi][ni] = (f32x4){0.f, 0.f, 0.f, 0.f};

  for (int k0 = 0; k0 < K; k0 += 32) {
    #pragma unroll
    for (int it = 0; it < 2; ++it) {
      const int chunk = w + it * 4;
      const int i     = chunk * 64 + lane;
      const int row   = i >> 2;
      const int c8    = (i & 3) << 3;
      const ushort* srcA = A  + (size_t)(brow + row) * K + k0 + c8;
      const ushort* srcB = Bt + (size_t)(bcol + row) * K + k0 + c8;
      __builtin_amdgcn_global_load_lds(GLOBAL_AS(srcA), LDS_AS(sA + chunk * 512), 16, 0, 0);
      __builtin_amdgcn_global_load_lds(GLOBAL_AS(srcB), LDS_AS(sB + chunk * 512), 16, 0, 0);
    }
    __syncthreads();

    bf16x8 af[4], bfr[4];
    #pragma unroll
    for (int mi = 0; mi < 4; ++mi)
      af[mi] = *reinterpret_cast<const bf16x8*>(sA + (wr * 64 + mi * 16 + lr) * 32 + kq * 8);
    #pragma unroll
    for (int ni = 0; ni < 4; ++ni)
      bfr[ni] = *reinterpret_cast<const bf16x8*>(sB + (wc * 64 + ni * 16 + lr) * 32 + kq * 8);
    #pragma unroll
    for (int mi = 0; mi < 4; ++mi)
      #pragma unroll
      for (int ni = 0; ni < 4; ++ni)
        acc[mi][ni] = __builtin_amdgcn_mfma_f32_16x16x32_bf16(af[mi], bfr[ni], acc[mi][ni], 0, 0, 0);
    __syncthreads();
  }

  #pragma unroll
  for (int mi = 0; mi < 4; ++mi) {
    #pragma unroll
    for (int ni = 0; ni < 4; ++ni) {
      const int col = bcol + wc * 64 + ni * 16 + lr;
      const float bb = bias[col];
      if (MODE == 0) {
        const int which = col >> 9;
        const int nn    = col & 511;
        ushort* dst = (which == 0) ? Cq : ((which == 1) ? Ck : Cv);
        #pragma unroll
        for (int r = 0; r < 4; ++r) {
          const int row = brow + wr * 64 + mi * 16 + kq * 4 + r;
          dst[(size_t)row * DD + nn] = f2bf(acc[mi][ni][r] + bb);
        }
      } else {
        #pragma unroll
        for (int r = 0; r < 4; ++r) {
          const int row = brow + wr * 64 + mi * 16 + kq * 4 + r;
          Cf[(size_t)row * N + col] = acc[mi][ni][r] + bb;
        }
      }
    }
  }
}

// ---------------- fused block-sum of K,V -> Khi/Klo/Vb (no atomics) ----------
// One block per (b,s). 4 waves: wave kbq sums kb = kbq*16..kbq*16+15 in regs,
// LDS tree across waves, then wave 0 emits Khi/Klo, wave 1 emits Vb.
__global__ __launch_bounds__(256) void sumkv_fused(
    const ushort* __restrict__ K, const ushort* __restrict__ V,
    ushort* __restrict__ Khi, ushort* __restrict__ Klo, ushort* __restrict__ Vb)
{
  __shared__ float kbuf[4][64][9];
  __shared__ float vbuf[4][64][9];
  const int bs   = blockIdx.x;          // b*64 + s
  const int b    = bs >> 6, s = bs & 63;
  const int lane = threadIdx.x & 63;
  const int kbq  = threadIdx.x >> 6;
  const size_t rowbase = ((size_t)b * LL + s) * DD + lane * 8;

  float ak[8] = {0,0,0,0,0,0,0,0}, av[8] = {0,0,0,0,0,0,0,0};
  #pragma unroll
  for (int i = 0; i < 16; ++i) {
    const size_t off = rowbase + (size_t)(kbq * 16 + i) * BS * DD;
    uint4 ku = *reinterpret_cast<const uint4*>(K + off);
    uint4 vu = *reinterpret_cast<const uint4*>(V + off);
    ak[0] += bflo(ku.x); ak[1] += bfhi(ku.x); ak[2] += bflo(ku.y); ak[3] += bfhi(ku.y);
    ak[4] += bflo(ku.z); ak[5] += bfhi(ku.z); ak[6] += bflo(ku.w); ak[7] += bfhi(ku.w);
    av[0] += bflo(vu.x); av[1] += bfhi(vu.x); av[2] += bflo(vu.y); av[3] += bfhi(vu.y);
    av[4] += bflo(vu.z); av[5] += bfhi(vu.z); av[6] += bflo(vu.w); av[7] += bfhi(vu.w);
  }
  #pragma unroll
  for (int j = 0; j < 8; ++j) { kbuf[kbq][lane][j] = ak[j]; vbuf[kbq][lane][j] = av[j]; }
  __syncthreads();

  const size_t wbase = (size_t)bs * DD + lane * 8;
  if (kbq == 0) {
    uint4 hi4, lo4;
    uint* hp = reinterpret_cast<uint*>(&hi4);
    uint* lp = reinterpret_cast<uint*>(&lo4);
    #pragma unroll
    for (int p = 0; p < 4; ++p) {
      uint hw = 0, lw = 0;
      #pragma unroll
      for (int q = 0; q < 2; ++q) {
        const int j = p * 2 + q;
        const float t = kbuf[0][lane][j] + kbuf[1][lane][j] +
                        kbuf[2][lane][j] + kbuf[3][lane][j];
        const ushort h = f2bf(t);
        const ushort l = f2bf(t - bf2f(h));
        hw |= (uint)h << (16 * q);
        lw |= (uint)l << (16 * q);
      }
      hp[p] = hw; lp[p] = lw;
    }
    *reinterpret_cast<uint4*>(Khi + wbase) = hi4;
    *reinterpret_cast<uint4*>(Klo + wbase) = lo4;
  } else if (kbq == 1) {
    uint4 o4;
    uint* op = reinterpret_cast<uint*>(&o4);
    #pragma unroll
    for (int p = 0; p < 4; ++p) {
      uint w = 0;
      #pragma unroll
      for (int q = 0; q < 2; ++q) {
        const int j = p * 2 + q;
        const float t = vbuf[0][lane][j] + vbuf[1][lane][j] +
                        vbuf[2][lane][j] + vbuf[3][lane][j];
        w |= (uint)f2bf(t) << (16 * q);
      }
      op[p] = w;
    }
    *reinterpret_cast<uint4*>(Vb + wbase) = o4;
  }
}

// ---------------- MFMA two-pass block attention ------------------------------
__global__ __launch_bounds__(256) void attn_mfma(
    const ushort* __restrict__ Q, const ushort* __restrict__ Kg,
    const ushort* __restrict__ Vg, const ushort* __restrict__ Khi,
    const ushort* __restrict__ Klo, const ushort* __restrict__ Vsb,
    ushort* __restrict__ X)
{
  __shared__ __align__(16) ushort sA[64 * 64];   // K, then Khi
  __shared__ __align__(16) ushort sC[64 * 64];   // Klo (pass 2)
  __shared__ __align__(16) ushort sVt[64 * 64];  // V^T, then Vsum^T
  __shared__ __align__(16) ushort sP[64 * 64];   // P (per-wave 16-row slices)
  const int n = blockIdx.x, h = blockIdx.y, b = blockIdx.z;
  const int tid  = threadIdx.x;
  const int lane = tid & 63;
  const int w    = tid >> 6;
  const int lr   = lane & 15, hi4 = lane >> 4;
  const float scale = 0.125f;

  const size_t tbase = ((size_t)(b * LL + n * BS)) * DD + h * HDIM;
  const size_t sbase = ((size_t)(b * BS)) * DD + h * HDIM;

  uint4 k1[2], v1[2], k2h[2], k2l[2], v2[2];
  int rr[2], cc[2];
  #pragma unroll
  for (int it = 0; it < 2; ++it) {
    const int i  = tid + it * 256;      // 0..511
    const int r  = i >> 3;
    const int c8 = (i & 7) << 3;
    rr[it] = r; cc[it] = c8;
    const size_t g1 = tbase + (size_t)r * DD + c8;
    const size_t g2 = sbase + (size_t)r * DD + c8;
    k1[it]  = *reinterpret_cast<const uint4*>(Kg  + g1);
    v1[it]  = *reinterpret_cast<const uint4*>(Vg  + g1);
    k2h[it] = *reinterpret_cast<const uint4*>(Khi + g2);
    k2l[it] = *reinterpret_cast<const uint4*>(Klo + g2);
    v2[it]  = *reinterpret_cast<const uint4*>(Vsb + g2);
  }
  bf16x8 qf[2];
  #pragma unroll
  for (int ks = 0; ks < 2; ++ks)
    qf[ks] = *reinterpret_cast<const bf16x8*>(
        Q + tbase + (size_t)(w * 16 + lr) * DD + ks * 32 + hi4 * 8);

  #pragma unroll
  for (int it = 0; it < 2; ++it) {
    *reinterpret_cast<uint4*>(&sA[swb(rr[it], cc[it] << 1)]) = k1[it];
    const uint u[4] = {v1[it].x, v1[it].y, v1[it].z, v1[it].w};
    #pragma unroll
    for (int j = 0; j < 4; ++j) {
      sVt[swb(cc[it] + 2 * j,     rr[it] << 1)] = (ushort)(u[j] & 0xffff);
      sVt[swb(cc[it] + 2 * j + 1, rr[it] << 1)] = (ushort)(u[j] >> 16);
    }
  }
  __syncthreads();

  f32x4 xacc[4];
  #pragma unroll
  for (int dt = 0; dt < 4; ++dt) xacc[dt] = (f32x4){0.f, 0.f, 0.f, 0.f};

  // ================= PASS 1 =================
  {
    f32x4 st[4];
    #pragma unroll
    for (int t = 0; t < 4; ++t) st[t] = (f32x4){0.f, 0.f, 0.f, 0.f};
    #pragma unroll
    for (int ks = 0; ks < 2; ++ks) {
      #pragma unroll
      for (int t = 0; t < 4; ++t) {
        bf16x8 kf = *reinterpret_cast<const bf16x8*>(
            &sA[swb(t * 16 + lr, (ks * 32 + hi4 * 8) << 1)]);
        st[t] = __builtin_amdgcn_mfma_f32_16x16x32_bf16(kf, qf[ks], st[t], 0, 0, 0);
      }
    }
    float e[4][4];
    float mx = -1e30f;
    #pragma unroll
    for (int t = 0; t < 4; ++t)
      #pragma unroll
      for (int r = 0; r < 4; ++r) { e[t][r] = st[t][r] * scale; mx = fmaxf(mx, e[t][r]); }
    mx = fmaxf(mx, __shfl_xor(mx, 16));
    mx = fmaxf(mx, __shfl_xor(mx, 32));
    float sum = 0.f;
    #pragma unroll
    for (int t = 0; t < 4; ++t)
      #pragma unroll
      for (int r = 0; r < 4; ++r) { e[t][r] = __expf(e[t][r] - mx); sum += e[t][r]; }
    sum += __shfl_xor(sum, 16);
    sum += __shfl_xor(sum, 32);
    const float inv = 1.0f / sum;
    #pragma unroll
    for (int t = 0; t < 4; ++t) {
      ushort4 p4;
      p4.x = f2bf(e[t][0] * inv); p4.y = f2bf(e[t][1] * inv);
      p4.z = f2bf(e[t][2] * inv); p4.w = f2bf(e[t][3] * inv);
      *reinterpret_cast<ushort4*>(&sP[swb(w * 16 + lr, (t * 16 + hi4 * 4) << 1)]) = p4;
    }
    #pragma unroll
    for (int ks = 0; ks < 2; ++ks) {
      bf16x8 pa = *reinterpret_cast<const bf16x8*>(
          &sP[swb(w * 16 + lr, (ks * 32 + hi4 * 8) << 1)]);
      #pragma unroll
      for (int dt = 0; dt < 4; ++dt) {
        bf16x8 vb = *reinterpret_cast<const bf16x8*>(
            &sVt[swb(dt * 16 + lr, (ks * 32 + hi4 * 8) << 1)]);
        xacc[dt] = __builtin_amdgcn_mfma_f32_16x16x32_bf16(pa, vb, xacc[dt], 0, 0, 0);
      }
    }
  }
  __syncthreads();

  #pragma unroll
  for (int it = 0; it < 2; ++it) {
    *reinterpret_cast<uint4*>(&sA[swb(rr[it], cc[it] << 1)]) = k2h[it];
    *reinterpret_cast<uint4*>(&sC[swb(rr[it], cc[it] << 1)]) = k2l[it];
    const uint u[4] = {v2[it].x, v2[it].y, v2[it].z, v2[it].w};
    #pragma unroll
    for (int j = 0; j < 4; ++j) {
      sVt[swb(cc[it] + 2 * j,     rr[it] << 1)] = (ushort)(u[j] & 0xffff);
      sVt[swb(cc[it] + 2 * j + 1, rr[it] << 1)] = (ushort)(u[j] >> 16);
    }
  }
  __syncthreads();

  // ================= PASS 2 =================
  {
    f32x4 st[4];
    #pragma unroll
    for (int t = 0; t < 4; ++t) st[t] = (f32x4){0.f, 0.f, 0.f, 0.f};
    #pragma unroll
    for (int ks = 0; ks < 2; ++ks) {
      #pragma unroll
      for (int t = 0; t < 4; ++t) {
        bf16x8 kh = *reinterpret_cast<const bf16x8*>(
            &sA[swb(t * 16 + lr, (ks * 32 + hi4 * 8) << 1)]);
        st[t] = __builtin_amdgcn_mfma_f32_16x16x32_bf16(kh, qf[ks], st[t], 0, 0, 0);
        bf16x8 kl = *reinterpret_cast<const bf16x8*>(
            &sC[swb(t * 16 + lr, (ks * 32 + hi4 * 8) << 1)]);
        st[t] = __builtin_amdgcn_mfma_f32_16x16x32_bf16(kl, qf[ks], st[t], 0, 0, 0);
      }
    }
    float e[4][4];
    float mx = -1e30f;
    #pragma unroll
    for (int t = 0; t < 4; ++t)
      #pragma unroll
      for (int r = 0; r < 4; ++r) { e[t][r] = st[t][r] * scale; mx = fmaxf(mx, e[t][r]); }
    mx = fmaxf(mx, __shfl_xor(mx, 16));
    mx = fmaxf(mx, __shfl_xor(mx, 32));
    float sum = 0.f;
    #pragma unroll
    for (int t = 0; t < 4; ++t)
      #pragma unroll
      for (int r = 0; r < 4; ++r) { e[t][r] = __expf(e[t][r] - mx); sum += e[t][r]; }
    sum += __shfl_xor(sum, 16);
    sum += __shfl_xor(sum, 32);
    const float inv = 1.0f / sum;
    #pragma unroll
    for (int t = 0; t < 4; ++t) {
      ushort4 p4;
      p4.x = f2bf(e[t][0] * inv); p4.y = f2bf(e[t][1] * inv);
      p4.z = f2bf(e[t][2] * inv); p4.w = f2bf(e[t][3] * inv);
      *reinterpret_cast<ushort4*>(&sP[swb(w * 16 + lr, (t * 16 + hi4 * 4) << 1)]) = p4;
    }
    #pragma unroll
    for (int ks = 0; ks < 2; ++ks) {
      bf16x8 pa = *reinterpret_cast<const bf16x8*>(
          &sP[swb(w * 16 + lr, (ks * 32 + hi4 * 8) << 1)]);
      #pragma unroll
      for (int dt = 0; dt < 4; ++dt) {
        bf16x8 vb = *reinterpret_cast<const bf16x8*>(
            &sVt[swb(dt * 16 + lr, (ks * 32 + hi4 * 8) << 1)]);
        xacc[dt] = __builtin_amdgcn_mfma_f32_16x16x32_bf16(pa, vb, xacc[dt], 0, 0, 0);
      }
    }
  }

  #pragma unroll
  for (int dt = 0; dt < 4; ++dt)
    #pragma unroll
    for (int r = 0; r < 4; ++r)
      X[tbase + (size_t)(w * 16 + hi4 * 4 + r) * DD + dt * 16 + lr] = f2bf(xacc[dt][r]);
}

// ---------------- launcher ---------------------------------------------------
extern "C" void kernel_launch(void* const* d_in, const int* in_sizes, int n_in,
                              void* d_out, int out_size, void* d_ws, size_t ws_size,
                              hipStream_t stream) {
  const float* x_in = (const float*)d_in[0];
  const float* Wq   = (const float*)d_in[1];
  const float* bq   = (const float*)d_in[2];
  const float* Wk   = (const float*)d_in[3];
  const float* bk   = (const float*)d_in[4];
  const float* Wv   = (const float*)d_in[5];
  const float* bv   = (const float*)d_in[6];
  const float* Wout = (const float*)d_in[9];
  const float* bout = (const float*)d_in[10];
  float* out = (float*)d_out;

  const size_t NTOK = (size_t)MTOT * DD;          // 8,388,608 elems
  const size_t NSUM = (size_t)BB * BS * DD;       // 131072 elems
  char* ws = (char*)d_ws;
  ushort* xb      = (ushort*)ws;            ws += NTOK * 2;
  ushort* Qb      = (ushort*)ws;            ws += NTOK * 2;
  ushort* Kb      = (ushort*)ws;            ws += NTOK * 2;
  ushort* Vb      = (ushort*)ws;            ws += NTOK * 2;
  ushort* Xb      = (ushort*)ws;            ws += NTOK * 2;
  ushort* Wqkv_t  = (ushort*)ws;            ws += (size_t)1536 * 512 * 2;
  ushort* Wout_t  = (ushort*)ws;            ws += (size_t)512 * 512 * 2;
  float*  bias_qkv= (float*)ws;             ws += 2048 * 4;
  ushort* KhiB    = (ushort*)ws;            ws += NSUM * 2;
  ushort* KloB    = (ushort*)ws;            ws += NSUM * 2;
  ushort* VsB     = (ushort*)ws;            ws += NSUM * 2;

  f32_to_bf16_vec<<<NTOK / 4 / 256, 256, 0, stream>>>(x_in, xb);
  dim3 tg(16, 16);
  transpose_cast<<<tg, 256, 0, stream>>>(Wq,   Wqkv_t,               512, 512);
  transpose_cast<<<tg, 256, 0, stream>>>(Wk,   Wqkv_t + 512 * 512,   512, 512);
  transpose_cast<<<tg, 256, 0, stream>>>(Wv,   Wqkv_t + 1024 * 512,  512, 512);
  transpose_cast<<<tg, 256, 0, stream>>>(Wout, Wout_t,               512, 512);
  concat_bias<<<1, 512, 0, stream>>>(bq, bk, bv, bias_qkv);

  gemm_mfma<0><<<dim3(1536 / 128, MTOT / 128), 256, 0, stream>>>(
      xb, Wqkv_t, bias_qkv, Qb, Kb, Vb, nullptr, MTOT, 1536, 512);

  sumkv_fused<<<BB * BS, 256, 0, stream>>>(Kb, Vb, KhiB, KloB, VsB);

  attn_mfma<<<dim3(NBLK, HH, BB), 256, 0, stream>>>(Qb, Kb, Vb, KhiB, KloB, VsB, Xb);

  gemm_mfma<1><<<dim3(512 / 128, MTOT / 128), 256, 0, stream>>>(
      Xb, Wout_t, bout, nullptr, nullptr, nullptr, out, MTOT, 512, 512);
}

// Round 5
// 113.271 us; speedup vs baseline: 4.8421x; 1.1010x over previous
//
#include <hip/hip_runtime.h>

// SinkhornAttention — round 5: phase-interleaved 3-deep pipelined MFMA GEMM
// (T2 swizzle + T3/T4 counted-vmcnt + T5 setprio + T1 XCD swizzle).
// Math simplification (round 0, verified): sorted_key/value reduce to the
// block-sum of K/V; Wsort/bsort are dead.

constexpr int BB   = 4;
constexpr int LL   = 4096;
constexpr int DD   = 512;
constexpr int HH   = 8;
constexpr int HDIM = 64;
constexpr int BS   = 64;
constexpr int NBLK = 64;
constexpr int MTOT = BB * LL;   // 16384

using f32x4  = __attribute__((ext_vector_type(4))) float;
typedef __attribute__((ext_vector_type(8))) __bf16 bf16x8;

static __device__ __forceinline__ ushort f2bf(float f) {
  uint u = __float_as_uint(f);
  uint r = (u + 0x7fffu + ((u >> 16) & 1u)) >> 16;   // RNE
  return (ushort)r;
}
static __device__ __forceinline__ float bf2f(ushort u) { return __uint_as_float((uint)u << 16); }
static __device__ __forceinline__ float bflo(uint u) { return __uint_as_float(u << 16); }
static __device__ __forceinline__ float bfhi(uint u) { return __uint_as_float(u & 0xffff0000u); }

// attention-tile swizzle (64x64 bf16 tile, row stride 128 B)
static __device__ __forceinline__ int swb(int row, int cb) {
  return (row << 6) + ((cb ^ ((row & 7) << 4)) >> 1);
}

#define GLOBAL_AS(p) ((const __attribute__((address_space(1))) void*)(p))
#define LDS_AS(p)    ((__attribute__((address_space(3))) void*)(p))
#define SB0()        __builtin_amdgcn_sched_barrier(0)

// ---------------- f32 -> bf16 straight cast (4 elems/thread) -----------------
__global__ __launch_bounds__(256) void f32_to_bf16_vec(
    const float* __restrict__ src, ushort* __restrict__ dst)
{
  const int i = blockIdx.x * 256 + threadIdx.x;
  float4 v = reinterpret_cast<const float4*>(src)[i];
  ushort4 o;
  o.x = f2bf(v.x); o.y = f2bf(v.y); o.z = f2bf(v.z); o.w = f2bf(v.w);
  reinterpret_cast<ushort4*>(dst)[i] = o;
}

// ---------------- transpose + cast: src f32 [R][C] -> dst bf16 [C][R] --------
__global__ __launch_bounds__(256) void transpose_cast(
    const float* __restrict__ src, ushort* __restrict__ dst, int R, int C)
{
  __shared__ float tile[32][33];
  const int tx = threadIdx.x & 31, ty = threadIdx.x >> 5;   // 32 x 8
  const int r0 = blockIdx.y * 32, c0 = blockIdx.x * 32;
  #pragma unroll
  for (int q = 0; q < 4; ++q)
    tile[ty + 8 * q][tx] = src[(size_t)(r0 + ty + 8 * q) * C + c0 + tx];
  __syncthreads();
  #pragma unroll
  for (int q = 0; q < 4; ++q)
    dst[(size_t)(c0 + ty + 8 * q) * R + r0 + tx] = f2bf(tile[tx][ty + 8 * q]);
}

// ---------------- concat Q/K/V biases into one f32[1536] ---------------------
__global__ void concat_bias(const float* __restrict__ bq, const float* __restrict__ bk,
                            const float* __restrict__ bv, float* __restrict__ o)
{
  const int t = threadIdx.x;   // 512
  o[t] = bq[t]; o[512 + t] = bk[t]; o[1024 + t] = bv[t];
}

// ---------------- pipelined MFMA GEMM: C[M,TNtot] = A[M,512] @ Bt^T + bias ---
// Tile 128 x TN, BK=64, 8 waves (2M x 4N), 3-deep LDS pipeline (stage t+2
// while computing t), 2 phases per K-tile, counted vmcnt gates, LDS chunk
// XOR-swizzle (chunk ^= row&7) for conflict-free ds_read_b128.
// MODE 0: scatter bf16 into Q/K/V (col>>9 selects). MODE 1: f32 out.
template<int MODE, int TN>
__global__ __launch_bounds__(512, 2) void gemm_pipe(
    const ushort* __restrict__ A, const ushort* __restrict__ Bt,
    const float* __restrict__ bias,
    ushort* __restrict__ Cq, ushort* __restrict__ Ck, ushort* __restrict__ Cv,
    float* __restrict__ Cf, int N, int NBX)
{
  constexpr int NF  = TN / 64;        // B col-frags per wave (3 or 2)
  constexpr int K   = 512;
  constexpr int NT  = K / 64;         // 8 K-tiles
  __shared__ __align__(16) ushort sA[3][128 * 64];
  __shared__ __align__(16) ushort sB[3][TN * 64];

  const int tid  = threadIdx.x;
  const int lane = tid & 63;
  const int w    = tid >> 6;
  const int wr   = w >> 2;            // 0..1  M-half (64 rows)
  const int wc   = w & 3;             // 0..3  N-quarter (TN/4 cols)
  const int lr   = lane & 15;
  const int kq   = lane >> 4;

  // XCD-chunked block swizzle (grid % 8 == 0), nb fastest within a chunk
  const int nwg  = NBX * 128;
  const int cpx  = nwg >> 3;
  const int swz  = (blockIdx.x & 7) * cpx + (blockIdx.x >> 3);
  const int nb   = swz % NBX;
  const int mb   = swz / NBX;
  const int brow = mb * 128;
  const int bcol = nb * TN;

  // stage one 16B chunk: LDS dest wave-uniform base (lane auto-offset);
  // global source pre-swizzled so LDS[row][ch] holds col (ch^(row&7)).
  auto stageA = [&](int buf, int t, int j) {
    const int c   = j * 512 + tid;
    const int row = c >> 3, ch = c & 7;
    const ushort* src = A + (size_t)(brow + row) * K + t * 64 + ((ch ^ (row & 7)) << 3);
    __builtin_amdgcn_global_load_lds(GLOBAL_AS(src),
        LDS_AS(&sA[buf][(j * 512 + (w << 6)) << 3]), 16, 0, 0);
  };
  auto stageB = [&](int buf, int t, int j) {
    const int c   = j * 512 + tid;
    const int row = c >> 3, ch = c & 7;
    const ushort* src = Bt + (size_t)(bcol + row) * K + t * 64 + ((ch ^ (row & 7)) << 3);
    __builtin_amdgcn_global_load_lds(GLOBAL_AS(src),
        LDS_AS(&sB[buf][(j * 512 + (w << 6)) << 3]), 16, 0, 0);
  };
  // swizzled fragment reads
  auto ldA = [&](int buf, int mf, int ks) -> bf16x8 {
    const int row = (wr << 6) + (mf << 4) + lr;
    const int kc  = ((ks << 2) + kq) ^ (row & 7);
    return *reinterpret_cast<const bf16x8*>(&sA[buf][(row << 6) + (kc << 3)]);
  };
  auto ldB = [&](int buf, int nf, int ks) -> bf16x8 {
    const int row = wc * (TN >> 2) + (nf << 4) + lr;
    const int kc  = ((ks << 2) + kq) ^ (row & 7);
    return *reinterpret_cast<const bf16x8*>(&sB[buf][(row << 6) + (kc << 3)]);
  };

  f32x4 acc[4][NF];
  #pragma unroll
  for (int mf = 0; mf < 4; ++mf)
    #pragma unroll
    for (int nf = 0; nf < NF; ++nf)
      acc[mf][nf] = (f32x4){0.f, 0.f, 0.f, 0.f};

  // ---- prologue: stage tiles 0 and 1, publish tile 0
  #pragma unroll
  for (int j = 0; j < 2; ++j) stageA(0, 0, j);
  #pragma unroll
  for (int j = 0; j < NF; ++j) stageB(0, 0, j);
  #pragma unroll
  for (int j = 0; j < 2; ++j) stageA(1, 1, j);
  #pragma unroll
  for (int j = 0; j < NF; ++j) stageB(1, 1, j);
  if constexpr (NF == 3) asm volatile("s_waitcnt vmcnt(5)" ::: "memory");
  else                   asm volatile("s_waitcnt vmcnt(4)" ::: "memory");
  SB0(); __builtin_amdgcn_s_barrier(); SB0();

  for (int t = 0; t < NT; ++t) {
    const int buf  = t % 3;
    const int nbuf = (t + 2) % 3;
    const bool more = (t + 2) < NT;
    // ======== phase A: k-step 0 ========
    bf16x8 a0[4], b0[NF];
    #pragma unroll
    for (int mf = 0; mf < 4; ++mf) a0[mf] = ldA(buf, mf, 0);
    #pragma unroll
    for (int nf = 0; nf < NF; ++nf) b0[nf] = ldB(buf, nf, 0);
    if (more) { stageA(nbuf, t + 2, 0); stageA(nbuf, t + 2, 1); }
    SB0(); __builtin_amdgcn_s_barrier(); SB0();
    __builtin_amdgcn_s_setprio(1);
    #pragma unroll
    for (int mf = 0; mf < 4; ++mf)
      #pragma unroll
      for (int nf = 0; nf < NF; ++nf)
        acc[mf][nf] = __builtin_amdgcn_mfma_f32_16x16x32_bf16(a0[mf], b0[nf], acc[mf][nf], 0, 0, 0);
    __builtin_amdgcn_s_setprio(0);
    SB0(); __builtin_amdgcn_s_barrier(); SB0();
    // ======== phase B: k-step 1 ========
    bf16x8 a1[4], b1[NF];
    #pragma unroll
    for (int mf = 0; mf < 4; ++mf) a1[mf] = ldA(buf, mf, 1);
    #pragma unroll
    for (int nf = 0; nf < NF; ++nf) b1[nf] = ldB(buf, nf, 1);
    if (more) {
      #pragma unroll
      for (int j = 0; j < NF; ++j) stageB(nbuf, t + 2, j);
    }
    SB0(); __builtin_amdgcn_s_barrier(); SB0();
    __builtin_amdgcn_s_setprio(1);
    #pragma unroll
    for (int mf = 0; mf < 4; ++mf)
      #pragma unroll
      for (int nf = 0; nf < NF; ++nf)
        acc[mf][nf] = __builtin_amdgcn_mfma_f32_16x16x32_bf16(a1[mf], b1[nf], acc[mf][nf], 0, 0, 0);
    __builtin_amdgcn_s_setprio(0);
    // tile-boundary gate: keep next-next tile's loads in flight, never 0
    if (more) {
      if constexpr (NF == 3) asm volatile("s_waitcnt vmcnt(5)" ::: "memory");
      else                   asm volatile("s_waitcnt vmcnt(4)" ::: "memory");
    } else {
      asm volatile("s_waitcnt vmcnt(0)" ::: "memory");
    }
    SB0(); __builtin_amdgcn_s_barrier(); SB0();
  }

  // ---- epilogue: bias + store (C/D layout: col=lane&15, row=(lane>>4)*4+r)
  #pragma unroll
  for (int nf = 0; nf < NF; ++nf) {
    const int col0 = bcol + wc * (TN >> 2) + nf * 16;   // wave-uniform
    const float bb = bias[col0 + lr];
    if (MODE == 0) {
      const int which = col0 >> 9;
      ushort* dst = (which == 0) ? Cq : ((which == 1) ? Ck : Cv);
      const int nn = (col0 & 511) + lr;
      #pragma unroll
      for (int mf = 0; mf < 4; ++mf)
        #pragma unroll
        for (int r = 0; r < 4; ++r) {
          const int row = brow + (wr << 6) + (mf << 4) + (kq << 2) + r;
          dst[(size_t)row * DD + nn] = f2bf(acc[mf][nf][r] + bb);
        }
    } else {
      #pragma unroll
      for (int mf = 0; mf < 4; ++mf)
        #pragma unroll
        for (int r = 0; r < 4; ++r) {
          const int row = brow + (wr << 6) + (mf << 4) + (kq << 2) + r;
          Cf[(size_t)row * N + col0 + lr] = acc[mf][nf][r] + bb;
        }
    }
  }
}

// ---------------- fused block-sum of K,V -> Khi/Klo/Vb (no atomics) ----------
__global__ __launch_bounds__(256) void sumkv_fused(
    const ushort* __restrict__ K, const ushort* __restrict__ V,
    ushort* __restrict__ Khi, ushort* __restrict__ Klo, ushort* __restrict__ Vb)
{
  __shared__ float kbuf[4][64][9];
  __shared__ float vbuf[4][64][9];
  const int bs   = blockIdx.x;          // b*64 + s
  const int b    = bs >> 6, s = bs & 63;
  const int lane = threadIdx.x & 63;
  const int kbq  = threadIdx.x >> 6;
  const size_t rowbase = ((size_t)b * LL + s) * DD + lane * 8;

  float ak[8] = {0,0,0,0,0,0,0,0}, av[8] = {0,0,0,0,0,0,0,0};
  #pragma unroll
  for (int i = 0; i < 16; ++i) {
    const size_t off = rowbase + (size_t)(kbq * 16 + i) * BS * DD;
    uint4 ku = *reinterpret_cast<const uint4*>(K + off);
    uint4 vu = *reinterpret_cast<const uint4*>(V + off);
    ak[0] += bflo(ku.x); ak[1] += bfhi(ku.x); ak[2] += bflo(ku.y); ak[3] += bfhi(ku.y);
    ak[4] += bflo(ku.z); ak[5] += bfhi(ku.z); ak[6] += bflo(ku.w); ak[7] += bfhi(ku.w);
    av[0] += bflo(vu.x); av[1] += bfhi(vu.x); av[2] += bflo(vu.y); av[3] += bfhi(vu.y);
    av[4] += bflo(vu.z); av[5] += bfhi(vu.z); av[6] += bflo(vu.w); av[7] += bfhi(vu.w);
  }
  #pragma unroll
  for (int j = 0; j < 8; ++j) { kbuf[kbq][lane][j] = ak[j]; vbuf[kbq][lane][j] = av[j]; }
  __syncthreads();

  const size_t wbase = (size_t)bs * DD + lane * 8;
  if (kbq == 0) {
    uint4 hi4, lo4;
    uint* hp = reinterpret_cast<uint*>(&hi4);
    uint* lp = reinterpret_cast<uint*>(&lo4);
    #pragma unroll
    for (int p = 0; p < 4; ++p) {
      uint hw = 0, lw = 0;
      #pragma unroll
      for (int q = 0; q < 2; ++q) {
        const int j = p * 2 + q;
        const float t = kbuf[0][lane][j] + kbuf[1][lane][j] +
                        kbuf[2][lane][j] + kbuf[3][lane][j];
        const ushort h = f2bf(t);
        const ushort l = f2bf(t - bf2f(h));
        hw |= (uint)h << (16 * q);
        lw |= (uint)l << (16 * q);
      }
      hp[p] = hw; lp[p] = lw;
    }
    *reinterpret_cast<uint4*>(Khi + wbase) = hi4;
    *reinterpret_cast<uint4*>(Klo + wbase) = lo4;
  } else if (kbq == 1) {
    uint4 o4;
    uint* op = reinterpret_cast<uint*>(&o4);
    #pragma unroll
    for (int p = 0; p < 4; ++p) {
      uint wv = 0;
      #pragma unroll
      for (int q = 0; q < 2; ++q) {
        const int j = p * 2 + q;
        const float t = vbuf[0][lane][j] + vbuf[1][lane][j] +
                        vbuf[2][lane][j] + vbuf[3][lane][j];
        wv |= (uint)f2bf(t) << (16 * q);
      }
      op[p] = wv;
    }
    *reinterpret_cast<uint4*>(Vb + wbase) = o4;
  }
}

// ---------------- MFMA two-pass block attention ------------------------------
__global__ __launch_bounds__(256) void attn_mfma(
    const ushort* __restrict__ Q, const ushort* __restrict__ Kg,
    const ushort* __restrict__ Vg, const ushort* __restrict__ Khi,
    const ushort* __restrict__ Klo, const ushort* __restrict__ Vsb,
    ushort* __restrict__ X)
{
  __shared__ __align__(16) ushort sA[64 * 64];   // K, then Khi
  __shared__ __align__(16) ushort sC[64 * 64];   // Klo (pass 2)
  __shared__ __align__(16) ushort sVt[64 * 64];  // V^T, then Vsum^T
  __shared__ __align__(16) ushort sP[64 * 64];   // P (per-wave 16-row slices)
  const int n = blockIdx.x, h = blockIdx.y, b = blockIdx.z;
  const int tid  = threadIdx.x;
  const int lane = tid & 63;
  const int w    = tid >> 6;
  const int lr   = lane & 15, hi4 = lane >> 4;
  const float scale = 0.125f;

  const size_t tbase = ((size_t)(b * LL + n * BS)) * DD + h * HDIM;
  const size_t sbase = ((size_t)(b * BS)) * DD + h * HDIM;

  uint4 k1[2], v1[2], k2h[2], k2l[2], v2[2];
  int rr[2], cc[2];
  #pragma unroll
  for (int it = 0; it < 2; ++it) {
    const int i  = tid + it * 256;      // 0..511
    const int r  = i >> 3;
    const int c8 = (i & 7) << 3;
    rr[it] = r; cc[it] = c8;
    const size_t g1 = tbase + (size_t)r * DD + c8;
    const size_t g2 = sbase + (size_t)r * DD + c8;
    k1[it]  = *reinterpret_cast<const uint4*>(Kg  + g1);
    v1[it]  = *reinterpret_cast<const uint4*>(Vg  + g1);
    k2h[it] = *reinterpret_cast<const uint4*>(Khi + g2);
    k2l[it] = *reinterpret_cast<const uint4*>(Klo + g2);
    v2[it]  = *reinterpret_cast<const uint4*>(Vsb + g2);
  }
  bf16x8 qf[2];
  #pragma unroll
  for (int ks = 0; ks < 2; ++ks)
    qf[ks] = *reinterpret_cast<const bf16x8*>(
        Q + tbase + (size_t)(w * 16 + lr) * DD + ks * 32 + hi4 * 8);

  #pragma unroll
  for (int it = 0; it < 2; ++it) {
    *reinterpret_cast<uint4*>(&sA[swb(rr[it], cc[it] << 1)]) = k1[it];
    const uint u[4] = {v1[it].x, v1[it].y, v1[it].z, v1[it].w};
    #pragma unroll
    for (int j = 0; j < 4; ++j) {
      sVt[swb(cc[it] + 2 * j,     rr[it] << 1)] = (ushort)(u[j] & 0xffff);
      sVt[swb(cc[it] + 2 * j + 1, rr[it] << 1)] = (ushort)(u[j] >> 16);
    }
  }
  __syncthreads();

  f32x4 xacc[4];
  #pragma unroll
  for (int dt = 0; dt < 4; ++dt) xacc[dt] = (f32x4){0.f, 0.f, 0.f, 0.f};

  // ================= PASS 1 =================
  {
    f32x4 st[4];
    #pragma unroll
    for (int t = 0; t < 4; ++t) st[t] = (f32x4){0.f, 0.f, 0.f, 0.f};
    #pragma unroll
    for (int ks = 0; ks < 2; ++ks) {
      #pragma unroll
      for (int t = 0; t < 4; ++t) {
        bf16x8 kf = *reinterpret_cast<const bf16x8*>(
            &sA[swb(t * 16 + lr, (ks * 32 + hi4 * 8) << 1)]);
        st[t] = __builtin_amdgcn_mfma_f32_16x16x32_bf16(kf, qf[ks], st[t], 0, 0, 0);
      }
    }
    float e[4][4];
    float mx = -1e30f;
    #pragma unroll
    for (int t = 0; t < 4; ++t)
      #pragma unroll
      for (int r = 0; r < 4; ++r) { e[t][r] = st[t][r] * scale; mx = fmaxf(mx, e[t][r]); }
    mx = fmaxf(mx, __shfl_xor(mx, 16));
    mx = fmaxf(mx, __shfl_xor(mx, 32));
    float sum = 0.f;
    #pragma unroll
    for (int t = 0; t < 4; ++t)
      #pragma unroll
      for (int r = 0; r < 4; ++r) { e[t][r] = __expf(e[t][r] - mx); sum += e[t][r]; }
    sum += __shfl_xor(sum, 16);
    sum += __shfl_xor(sum, 32);
    const float inv = 1.0f / sum;
    #pragma unroll
    for (int t = 0; t < 4; ++t) {
      ushort4 p4;
      p4.x = f2bf(e[t][0] * inv); p4.y = f2bf(e[t][1] * inv);
      p4.z = f2bf(e[t][2] * inv); p4.w = f2bf(e[t][3] * inv);
      *reinterpret_cast<ushort4*>(&sP[swb(w * 16 + lr, (t * 16 + hi4 * 4) << 1)]) = p4;
    }
    #pragma unroll
    for (int ks = 0; ks < 2; ++ks) {
      bf16x8 pa = *reinterpret_cast<const bf16x8*>(
          &sP[swb(w * 16 + lr, (ks * 32 + hi4 * 8) << 1)]);
      #pragma unroll
      for (int dt = 0; dt < 4; ++dt) {
        bf16x8 vb = *reinterpret_cast<const bf16x8*>(
            &sVt[swb(dt * 16 + lr, (ks * 32 + hi4 * 8) << 1)]);
        xacc[dt] = __builtin_amdgcn_mfma_f32_16x16x32_bf16(pa, vb, xacc[dt], 0, 0, 0);
      }
    }
  }
  __syncthreads();

  #pragma unroll
  for (int it = 0; it < 2; ++it) {
    *reinterpret_cast<uint4*>(&sA[swb(rr[it], cc[it] << 1)]) = k2h[it];
    *reinterpret_cast<uint4*>(&sC[swb(rr[it], cc[it] << 1)]) = k2l[it];
    const uint u[4] = {v2[it].x, v2[it].y, v2[it].z, v2[it].w};
    #pragma unroll
    for (int j = 0; j < 4; ++j) {
      sVt[swb(cc[it] + 2 * j,     rr[it] << 1)] = (ushort)(u[j] & 0xffff);
      sVt[swb(cc[it] + 2 * j + 1, rr[it] << 1)] = (ushort)(u[j] >> 16);
    }
  }
  __syncthreads();

  // ================= PASS 2 =================
  {
    f32x4 st[4];
    #pragma unroll
    for (int t = 0; t < 4; ++t) st[t] = (f32x4){0.f, 0.f, 0.f, 0.f};
    #pragma unroll
    for (int ks = 0; ks < 2; ++ks) {
      #pragma unroll
      for (int t = 0; t < 4; ++t) {
        bf16x8 kh = *reinterpret_cast<const bf16x8*>(
            &sA[swb(t * 16 + lr, (ks * 32 + hi4 * 8) << 1)]);
        st[t] = __builtin_amdgcn_mfma_f32_16x16x32_bf16(kh, qf[ks], st[t], 0, 0, 0);
        bf16x8 kl = *reinterpret_cast<const bf16x8*>(
            &sC[swb(t * 16 + lr, (ks * 32 + hi4 * 8) << 1)]);
        st[t] = __builtin_amdgcn_mfma_f32_16x16x32_bf16(kl, qf[ks], st[t], 0, 0, 0);
      }
    }
    float e[4][4];
    float mx = -1e30f;
    #pragma unroll
    for (int t = 0; t < 4; ++t)
      #pragma unroll
      for (int r = 0; r < 4; ++r) { e[t][r] = st[t][r] * scale; mx = fmaxf(mx, e[t][r]); }
    mx = fmaxf(mx, __shfl_xor(mx, 16));
    mx = fmaxf(mx, __shfl_xor(mx, 32));
    float sum = 0.f;
    #pragma unroll
    for (int t = 0; t < 4; ++t)
      #pragma unroll
      for (int r = 0; r < 4; ++r) { e[t][r] = __expf(e[t][r] - mx); sum += e[t][r]; }
    sum += __shfl_xor(sum, 16);
    sum += __shfl_xor(sum, 32);
    const float inv = 1.0f / sum;
    #pragma unroll
    for (int t = 0; t < 4; ++t) {
      ushort4 p4;
      p4.x = f2bf(e[t][0] * inv); p4.y = f2bf(e[t][1] * inv);
      p4.z = f2bf(e[t][2] * inv); p4.w = f2bf(e[t][3] * inv);
      *reinterpret_cast<ushort4*>(&sP[swb(w * 16 + lr, (t * 16 + hi4 * 4) << 1)]) = p4;
    }
    #pragma unroll
    for (int ks = 0; ks < 2; ++ks) {
      bf16x8 pa = *reinterpret_cast<const bf16x8*>(
          &sP[swb(w * 16 + lr, (ks * 32 + hi4 * 8) << 1)]);
      #pragma unroll
      for (int dt = 0; dt < 4; ++dt) {
        bf16x8 vb = *reinterpret_cast<const bf16x8*>(
            &sVt[swb(dt * 16 + lr, (ks * 32 + hi4 * 8) << 1)]);
        xacc[dt] = __builtin_amdgcn_mfma_f32_16x16x32_bf16(pa, vb, xacc[dt], 0, 0, 0);
      }
    }
  }

  #pragma unroll
  for (int dt = 0; dt < 4; ++dt)
    #pragma unroll
    for (int r = 0; r < 4; ++r)
      X[tbase + (size_t)(w * 16 + hi4 * 4 + r) * DD + dt * 16 + lr] = f2bf(xacc[dt][r]);
}

// ---------------- launcher ---------------------------------------------------
extern "C" void kernel_launch(void* const* d_in, const int* in_sizes, int n_in,
                              void* d_out, int out_size, void* d_ws, size_t ws_size,
                              hipStream_t stream) {
  const float* x_in = (const float*)d_in[0];
  const float* Wq   = (const float*)d_in[1];
  const float* bq   = (const float*)d_in[2];
  const float* Wk   = (const float*)d_in[3];
  const float* bk   = (const float*)d_in[4];
  const float* Wv   = (const float*)d_in[5];
  const float* bv   = (const float*)d_in[6];
  const float* Wout = (const float*)d_in[9];
  const float* bout = (const float*)d_in[10];
  float* out = (float*)d_out;

  const size_t NTOK = (size_t)MTOT * DD;          // 8,388,608 elems
  const size_t NSUM = (size_t)BB * BS * DD;       // 131072 elems
  char* ws = (char*)d_ws;
  ushort* xb      = (ushort*)ws;            ws += NTOK * 2;
  ushort* Qb      = (ushort*)ws;            ws += NTOK * 2;
  ushort* Kb      = (ushort*)ws;            ws += NTOK * 2;
  ushort* Vb      = (ushort*)ws;            ws += NTOK * 2;
  ushort* Xb      = (ushort*)ws;            ws += NTOK * 2;
  ushort* Wqkv_t  = (ushort*)ws;            ws += (size_t)1536 * 512 * 2;
  ushort* Wout_t  = (ushort*)ws;            ws += (size_t)512 * 512 * 2;
  float*  bias_qkv= (float*)ws;             ws += 2048 * 4;
  ushort* KhiB    = (ushort*)ws;            ws += NSUM * 2;
  ushort* KloB    = (ushort*)ws;            ws += NSUM * 2;
  ushort* VsB     = (ushort*)ws;            ws += NSUM * 2;

  f32_to_bf16_vec<<<NTOK / 4 / 256, 256, 0, stream>>>(x_in, xb);
  dim3 tg(16, 16);
  transpose_cast<<<tg, 256, 0, stream>>>(Wq,   Wqkv_t,               512, 512);
  transpose_cast<<<tg, 256, 0, stream>>>(Wk,   Wqkv_t + 512 * 512,   512, 512);
  transpose_cast<<<tg, 256, 0, stream>>>(Wv,   Wqkv_t + 1024 * 512,  512, 512);
  transpose_cast<<<tg, 256, 0, stream>>>(Wout, Wout_t,               512, 512);
  concat_bias<<<1, 512, 0, stream>>>(bq, bk, bv, bias_qkv);

  // QKV: tile 128x192, grid 8*128 = 1024 blocks (%8==0 for XCD swizzle)
  gemm_pipe<0, 192><<<1024, 512, 0, stream>>>(
      xb, Wqkv_t, bias_qkv, Qb, Kb, Vb, nullptr, 1536, 8);

  sumkv_fused<<<BB * BS, 256, 0, stream>>>(Kb, Vb, KhiB, KloB, VsB);

  attn_mfma<<<dim3(NBLK, HH, BB), 256, 0, stream>>>(Qb, Kb, Vb, KhiB, KloB, VsB, Xb);

  // out: tile 128x128, grid 4*128 = 512 blocks
  gemm_pipe<1, 128><<<512, 512, 0, stream>>>(
      Xb, Wout_t, bout, nullptr, nullptr, nullptr, out, 512, 4);
}

// Round 6
// 101.608 us; speedup vs baseline: 5.3979x; 1.1148x over previous
//
#include <hip/hip_runtime.h>

// SinkhornAttention — round 6: occupancy-fixed pipelined GEMM (128x128, BK=32,
// 3-deep, 48 KB LDS -> 3 blocks/CU, counted vmcnt, 1 barrier/K-step).
// Math simplification (round 0, verified): sorted_key/value reduce to the
// block-sum of K/V; Wsort/bsort are dead.

constexpr int BB   = 4;
constexpr int LL   = 4096;
constexpr int DD   = 512;
constexpr int HH   = 8;
constexpr int HDIM = 64;
constexpr int BS   = 64;
constexpr int NBLK = 64;
constexpr int MTOT = BB * LL;   // 16384

using f32x4  = __attribute__((ext_vector_type(4))) float;
typedef __attribute__((ext_vector_type(8))) __bf16 bf16x8;

static __device__ __forceinline__ ushort f2bf(float f) {
  uint u = __float_as_uint(f);
  uint r = (u + 0x7fffu + ((u >> 16) & 1u)) >> 16;   // RNE
  return (ushort)r;
}
static __device__ __forceinline__ float bf2f(ushort u) { return __uint_as_float((uint)u << 16); }
static __device__ __forceinline__ float bflo(uint u) { return __uint_as_float(u << 16); }
static __device__ __forceinline__ float bfhi(uint u) { return __uint_as_float(u & 0xffff0000u); }

// attention-tile swizzle (64x64 bf16 tile, row stride 128 B)
static __device__ __forceinline__ int swb(int row, int cb) {
  return (row << 6) + ((cb ^ ((row & 7) << 4)) >> 1);
}

#define GLOBAL_AS(p) ((const __attribute__((address_space(1))) void*)(p))
#define LDS_AS(p)    ((__attribute__((address_space(3))) void*)(p))
#define SB0()        __builtin_amdgcn_sched_barrier(0)

// ---------------- f32 -> bf16 straight cast (4 elems/thread) -----------------
__global__ __launch_bounds__(256) void f32_to_bf16_vec(
    const float* __restrict__ src, ushort* __restrict__ dst)
{
  const int i = blockIdx.x * 256 + threadIdx.x;
  float4 v = reinterpret_cast<const float4*>(src)[i];
  ushort4 o;
  o.x = f2bf(v.x); o.y = f2bf(v.y); o.z = f2bf(v.z); o.w = f2bf(v.w);
  reinterpret_cast<ushort4*>(dst)[i] = o;
}

// ------------- 4x transpose + cast (one launch): f32 [512][512] -> bf16^T ----
__global__ __launch_bounds__(256) void transpose_cast4(
    const float* __restrict__ Wq, const float* __restrict__ Wk,
    const float* __restrict__ Wv, const float* __restrict__ Wo,
    ushort* __restrict__ Wqkv_t, ushort* __restrict__ Wout_t)
{
  __shared__ float tile[32][33];
  const int z  = blockIdx.z;
  const float* src = (z == 0) ? Wq : (z == 1) ? Wk : (z == 2) ? Wv : Wo;
  ushort* dst = (z < 3) ? (Wqkv_t + (size_t)z * 512 * 512) : Wout_t;
  const int tx = threadIdx.x & 31, ty = threadIdx.x >> 5;   // 32 x 8
  const int r0 = blockIdx.y * 32, c0 = blockIdx.x * 32;
  #pragma unroll
  for (int q = 0; q < 4; ++q)
    tile[ty + 8 * q][tx] = src[(size_t)(r0 + ty + 8 * q) * 512 + c0 + tx];
  __syncthreads();
  #pragma unroll
  for (int q = 0; q < 4; ++q)
    dst[(size_t)(c0 + ty + 8 * q) * 512 + r0 + tx] = f2bf(tile[tx][ty + 8 * q]);
}

// ---------------- concat Q/K/V biases into one f32[1536] ---------------------
__global__ void concat_bias(const float* __restrict__ bq, const float* __restrict__ bk,
                            const float* __restrict__ bv, float* __restrict__ o)
{
  const int t = threadIdx.x;   // 512
  o[t] = bq[t]; o[512 + t] = bk[t]; o[1024 + t] = bv[t];
}

// ---------------- pipelined MFMA GEMM: C[M,N] = A[M,512] @ Bt[N,512]^T + b ---
// Tile 128x128, BK=32, 4 waves (2x2 of 64x64), 3-deep LDS pipeline
// (stage t+2 while computing t), counted vmcnt(4) gates, 1 raw barrier per
// K-step, 2-bit XOR granule swizzle for ~conflict-free ds_read_b128.
// MODE 0: scatter bf16 into Q/K/V (col>>9 selects). MODE 1: f32 out.
template<int MODE>
__global__ __launch_bounds__(256, 3) void gemm_pipe3(
    const ushort* __restrict__ A, const ushort* __restrict__ Bt,
    const float* __restrict__ bias,
    ushort* __restrict__ Cq, ushort* __restrict__ Ck, ushort* __restrict__ Cv,
    float* __restrict__ Cf, int N, int NBX)
{
  constexpr int K  = 512;
  constexpr int NT = K / 32;          // 16 K-steps
  __shared__ __align__(16) ushort sA[3][128 * 32];
  __shared__ __align__(16) ushort sB[3][128 * 32];

  const int tid  = threadIdx.x;
  const int lane = tid & 63;
  const int w    = tid >> 6;
  const int wr   = w >> 1, wc = w & 1;
  const int lr   = lane & 15;
  const int kq   = lane >> 4;

  // XCD-chunked block swizzle (grid % 8 == 0), nb fastest within a chunk
  const int nwg  = NBX * 128;
  const int cpx  = nwg >> 3;
  const int swz  = ((int)blockIdx.x & 7) * cpx + ((int)blockIdx.x >> 3);
  const int nb   = swz % NBX;
  const int mb   = swz / NBX;
  const int brow = mb * 128;
  const int bcol = nb * 128;

  // stage chunk j (0/1) of K-step t: 256 thr x 16 B; LDS linear, source
  // granule pre-swizzled (g ^= row&3) so reads de-bank.
  auto stageA = [&](int buf, int t, int j) {
    const int c   = j * 256 + tid;
    const int row = c >> 2, ch = c & 3;
    const ushort* src = A + (size_t)(brow + row) * K + t * 32 + ((ch ^ (row & 3)) << 3);
    __builtin_amdgcn_global_load_lds(GLOBAL_AS(src),
        LDS_AS(&sA[buf][(j * 256 + (w << 6)) << 3]), 16, 0, 0);
  };
  auto stageB = [&](int buf, int t, int j) {
    const int c   = j * 256 + tid;
    const int row = c >> 2, ch = c & 3;
    const ushort* src = Bt + (size_t)(bcol + row) * K + t * 32 + ((ch ^ (row & 3)) << 3);
    __builtin_amdgcn_global_load_lds(GLOBAL_AS(src),
        LDS_AS(&sB[buf][(j * 256 + (w << 6)) << 3]), 16, 0, 0);
  };
  auto ldA = [&](int buf, int mf) -> bf16x8 {
    const int row = (wr << 6) + (mf << 4) + lr;
    return *reinterpret_cast<const bf16x8*>(&sA[buf][(row << 5) + ((kq ^ (row & 3)) << 3)]);
  };
  auto ldB = [&](int buf, int nf) -> bf16x8 {
    const int row = (wc << 6) + (nf << 4) + lr;
    return *reinterpret_cast<const bf16x8*>(&sB[buf][(row << 5) + ((kq ^ (row & 3)) << 3)]);
  };

  f32x4 acc[4][4];
  #pragma unroll
  for (int mi = 0; mi < 4; ++mi)
    #pragma unroll
    for (int ni = 0; ni < 4; ++ni)
      acc[mi][ni] = (f32x4){0.f, 0.f, 0.f, 0.f};

  // ---- prologue: stage K-steps 0 and 1
  stageA(0, 0, 0); stageA(0, 0, 1); stageB(0, 0, 0); stageB(0, 0, 1);
  stageA(1, 1, 0); stageA(1, 1, 1); stageB(1, 1, 0); stageB(1, 1, 1);
  asm volatile("s_waitcnt vmcnt(4)" ::: "memory");
  SB0(); __builtin_amdgcn_s_barrier(); SB0();

  for (int t = 0; t < NT; ++t) {
    const int buf  = t % 3;
    const int nbuf = (t + 2) % 3;
    const bool more = (t + 2) < NT;

    bf16x8 af[4], bfr[4];
    #pragma unroll
    for (int mf = 0; mf < 4; ++mf) af[mf] = ldA(buf, mf);
    #pragma unroll
    for (int nf = 0; nf < 4; ++nf) bfr[nf] = ldB(buf, nf);
    if (more) { stageA(nbuf, t + 2, 0); stageA(nbuf, t + 2, 1);
                stageB(nbuf, t + 2, 0); stageB(nbuf, t + 2, 1); }
    SB0();
    __builtin_amdgcn_s_setprio(1);
    #pragma unroll
    for (int mi = 0; mi < 4; ++mi)
      #pragma unroll
      for (int ni = 0; ni < 4; ++ni)
        acc[mi][ni] = __builtin_amdgcn_mfma_f32_16x16x32_bf16(af[mi], bfr[ni], acc[mi][ni], 0, 0, 0);
    __builtin_amdgcn_s_setprio(0);
    SB0();
    // gate: t+1's 4 chunks must land; keep t+2's 4 in flight (never drain)
    if (more) asm volatile("s_waitcnt vmcnt(4)" ::: "memory");
    else      asm volatile("s_waitcnt vmcnt(0)" ::: "memory");
    SB0(); __builtin_amdgcn_s_barrier(); SB0();
  }

  // ---- epilogue: bias + store (C/D layout: col=lane&15, row=(lane>>4)*4+r)
  #pragma unroll
  for (int mi = 0; mi < 4; ++mi) {
    #pragma unroll
    for (int ni = 0; ni < 4; ++ni) {
      const int col = bcol + wc * 64 + ni * 16 + lr;
      const float bb = bias[col];
      if (MODE == 0) {
        const int which = col >> 9;
        const int nn    = col & 511;
        ushort* dst = (which == 0) ? Cq : ((which == 1) ? Ck : Cv);
        #pragma unroll
        for (int r = 0; r < 4; ++r) {
          const int row = brow + wr * 64 + mi * 16 + kq * 4 + r;
          dst[(size_t)row * DD + nn] = f2bf(acc[mi][ni][r] + bb);
        }
      } else {
        #pragma unroll
        for (int r = 0; r < 4; ++r) {
          const int row = brow + wr * 64 + mi * 16 + kq * 4 + r;
          Cf[(size_t)row * N + col] = acc[mi][ni][r] + bb;
        }
      }
    }
  }
}

// ---------------- fused block-sum of K,V -> Khi/Klo/Vb (no atomics) ----------
__global__ __launch_bounds__(256) void sumkv_fused(
    const ushort* __restrict__ K, const ushort* __restrict__ V,
    ushort* __restrict__ Khi, ushort* __restrict__ Klo, ushort* __restrict__ Vb)
{
  __shared__ float kbuf[4][64][9];
  __shared__ float vbuf[4][64][9];
  const int bs   = blockIdx.x;          // b*64 + s
  const int b    = bs >> 6, s = bs & 63;
  const int lane = threadIdx.x & 63;
  const int kbq  = threadIdx.x >> 6;
  const size_t rowbase = ((size_t)b * LL + s) * DD + lane * 8;

  float ak[8] = {0,0,0,0,0,0,0,0}, av[8] = {0,0,0,0,0,0,0,0};
  #pragma unroll
  for (int i = 0; i < 16; ++i) {
    const size_t off = rowbase + (size_t)(kbq * 16 + i) * BS * DD;
    uint4 ku = *reinterpret_cast<const uint4*>(K + off);
    uint4 vu = *reinterpret_cast<const uint4*>(V + off);
    ak[0] += bflo(ku.x); ak[1] += bfhi(ku.x); ak[2] += bflo(ku.y); ak[3] += bfhi(ku.y);
    ak[4] += bflo(ku.z); ak[5] += bfhi(ku.z); ak[6] += bflo(ku.w); ak[7] += bfhi(ku.w);
    av[0] += bflo(vu.x); av[1] += bfhi(vu.x); av[2] += bflo(vu.y); av[3] += bfhi(vu.y);
    av[4] += bflo(vu.z); av[5] += bfhi(vu.z); av[6] += bflo(vu.w); av[7] += bfhi(vu.w);
  }
  #pragma unroll
  for (int j = 0; j < 8; ++j) { kbuf[kbq][lane][j] = ak[j]; vbuf[kbq][lane][j] = av[j]; }
  __syncthreads();

  const size_t wbase = (size_t)bs * DD + lane * 8;
  if (kbq == 0) {
    uint4 hi4, lo4;
    uint* hp = reinterpret_cast<uint*>(&hi4);
    uint* lp = reinterpret_cast<uint*>(&lo4);
    #pragma unroll
    for (int p = 0; p < 4; ++p) {
      uint hw = 0, lw = 0;
      #pragma unroll
      for (int q = 0; q < 2; ++q) {
        const int j = p * 2 + q;
        const float t = kbuf[0][lane][j] + kbuf[1][lane][j] +
                        kbuf[2][lane][j] + kbuf[3][lane][j];
        const ushort h = f2bf(t);
        const ushort l = f2bf(t - bf2f(h));
        hw |= (uint)h << (16 * q);
        lw |= (uint)l << (16 * q);
      }
      hp[p] = hw; lp[p] = lw;
    }
    *reinterpret_cast<uint4*>(Khi + wbase) = hi4;
    *reinterpret_cast<uint4*>(Klo + wbase) = lo4;
  } else if (kbq == 1) {
    uint4 o4;
    uint* op = reinterpret_cast<uint*>(&o4);
    #pragma unroll
    for (int p = 0; p < 4; ++p) {
      uint wv = 0;
      #pragma unroll
      for (int q = 0; q < 2; ++q) {
        const int j = p * 2 + q;
        const float t = vbuf[0][lane][j] + vbuf[1][lane][j] +
                        vbuf[2][lane][j] + vbuf[3][lane][j];
        wv |= (uint)f2bf(t) << (16 * q);
      }
      op[p] = wv;
    }
    *reinterpret_cast<uint4*>(Vb + wbase) = o4;
  }
}

// ---------------- MFMA two-pass block attention ------------------------------
__global__ __launch_bounds__(256) void attn_mfma(
    const ushort* __restrict__ Q, const ushort* __restrict__ Kg,
    const ushort* __restrict__ Vg, const ushort* __restrict__ Khi,
    const ushort* __restrict__ Klo, const ushort* __restrict__ Vsb,
    ushort* __restrict__ X)
{
  __shared__ __align__(16) ushort sA[64 * 64];   // K, then Khi
  __shared__ __align__(16) ushort sC[64 * 64];   // Klo (pass 2)
  __shared__ __align__(16) ushort sVt[64 * 64];  // V^T, then Vsum^T
  __shared__ __align__(16) ushort sP[64 * 64];   // P (per-wave 16-row slices)
  const int n = blockIdx.x, h = blockIdx.y, b = blockIdx.z;
  const int tid  = threadIdx.x;
  const int lane = tid & 63;
  const int w    = tid >> 6;
  const int lr   = lane & 15, hi4 = lane >> 4;
  const float scale = 0.125f;

  const size_t tbase = ((size_t)(b * LL + n * BS)) * DD + h * HDIM;
  const size_t sbase = ((size_t)(b * BS)) * DD + h * HDIM;

  uint4 k1[2], v1[2], k2h[2], k2l[2], v2[2];
  int rr[2], cc[2];
  #pragma unroll
  for (int it = 0; it < 2; ++it) {
    const int i  = tid + it * 256;      // 0..511
    const int r  = i >> 3;
    const int c8 = (i & 7) << 3;
    rr[it] = r; cc[it] = c8;
    const size_t g1 = tbase + (size_t)r * DD + c8;
    const size_t g2 = sbase + (size_t)r * DD + c8;
    k1[it]  = *reinterpret_cast<const uint4*>(Kg  + g1);
    v1[it]  = *reinterpret_cast<const uint4*>(Vg  + g1);
    k2h[it] = *reinterpret_cast<const uint4*>(Khi + g2);
    k2l[it] = *reinterpret_cast<const uint4*>(Klo + g2);
    v2[it]  = *reinterpret_cast<const uint4*>(Vsb + g2);
  }
  bf16x8 qf[2];
  #pragma unroll
  for (int ks = 0; ks < 2; ++ks)
    qf[ks] = *reinterpret_cast<const bf16x8*>(
        Q + tbase + (size_t)(w * 16 + lr) * DD + ks * 32 + hi4 * 8);

  #pragma unroll
  for (int it = 0; it < 2; ++it) {
    *reinterpret_cast<uint4*>(&sA[swb(rr[it], cc[it] << 1)]) = k1[it];
    const uint u[4] = {v1[it].x, v1[it].y, v1[it].z, v1[it].w};
    #pragma unroll
    for (int j = 0; j < 4; ++j) {
      sVt[swb(cc[it] + 2 * j,     rr[it] << 1)] = (ushort)(u[j] & 0xffff);
      sVt[swb(cc[it] + 2 * j + 1, rr[it] << 1)] = (ushort)(u[j] >> 16);
    }
  }
  __syncthreads();

  f32x4 xacc[4];
  #pragma unroll
  for (int dt = 0; dt < 4; ++dt) xacc[dt] = (f32x4){0.f, 0.f, 0.f, 0.f};

  // ================= PASS 1 =================
  {
    f32x4 st[4];
    #pragma unroll
    for (int t = 0; t < 4; ++t) st[t] = (f32x4){0.f, 0.f, 0.f, 0.f};
    #pragma unroll
    for (int ks = 0; ks < 2; ++ks) {
      #pragma unroll
      for (int t = 0; t < 4; ++t) {
        bf16x8 kf = *reinterpret_cast<const bf16x8*>(
            &sA[swb(t * 16 + lr, (ks * 32 + hi4 * 8) << 1)]);
        st[t] = __builtin_amdgcn_mfma_f32_16x16x32_bf16(kf, qf[ks], st[t], 0, 0, 0);
      }
    }
    float e[4][4];
    float mx = -1e30f;
    #pragma unroll
    for (int t = 0; t < 4; ++t)
      #pragma unroll
      for (int r = 0; r < 4; ++r) { e[t][r] = st[t][r] * scale; mx = fmaxf(mx, e[t][r]); }
    mx = fmaxf(mx, __shfl_xor(mx, 16));
    mx = fmaxf(mx, __shfl_xor(mx, 32));
    float sum = 0.f;
    #pragma unroll
    for (int t = 0; t < 4; ++t)
      #pragma unroll
      for (int r = 0; r < 4; ++r) { e[t][r] = __expf(e[t][r] - mx); sum += e[t][r]; }
    sum += __shfl_xor(sum, 16);
    sum += __shfl_xor(sum, 32);
    const float inv = 1.0f / sum;
    #pragma unroll
    for (int t = 0; t < 4; ++t) {
      ushort4 p4;
      p4.x = f2bf(e[t][0] * inv); p4.y = f2bf(e[t][1] * inv);
      p4.z = f2bf(e[t][2] * inv); p4.w = f2bf(e[t][3] * inv);
      *reinterpret_cast<ushort4*>(&sP[swb(w * 16 + lr, (t * 16 + hi4 * 4) << 1)]) = p4;
    }
    #pragma unroll
    for (int ks = 0; ks < 2; ++ks) {
      bf16x8 pa = *reinterpret_cast<const bf16x8*>(
          &sP[swb(w * 16 + lr, (ks * 32 + hi4 * 8) << 1)]);
      #pragma unroll
      for (int dt = 0; dt < 4; ++dt) {
        bf16x8 vb = *reinterpret_cast<const bf16x8*>(
            &sVt[swb(dt * 16 + lr, (ks * 32 + hi4 * 8) << 1)]);
        xacc[dt] = __builtin_amdgcn_mfma_f32_16x16x32_bf16(pa, vb, xacc[dt], 0, 0, 0);
      }
    }
  }
  __syncthreads();

  #pragma unroll
  for (int it = 0; it < 2; ++it) {
    *reinterpret_cast<uint4*>(&sA[swb(rr[it], cc[it] << 1)]) = k2h[it];
    *reinterpret_cast<uint4*>(&sC[swb(rr[it], cc[it] << 1)]) = k2l[it];
    const uint u[4] = {v2[it].x, v2[it].y, v2[it].z, v2[it].w};
    #pragma unroll
    for (int j = 0; j < 4; ++j) {
      sVt[swb(cc[it] + 2 * j,     rr[it] << 1)] = (ushort)(u[j] & 0xffff);
      sVt[swb(cc[it] + 2 * j + 1, rr[it] << 1)] = (ushort)(u[j] >> 16);
    }
  }
  __syncthreads();

  // ================= PASS 2 =================
  {
    f32x4 st[4];
    #pragma unroll
    for (int t = 0; t < 4; ++t) st[t] = (f32x4){0.f, 0.f, 0.f, 0.f};
    #pragma unroll
    for (int ks = 0; ks < 2; ++ks) {
      #pragma unroll
      for (int t = 0; t < 4; ++t) {
        bf16x8 kh = *reinterpret_cast<const bf16x8*>(
            &sA[swb(t * 16 + lr, (ks * 32 + hi4 * 8) << 1)]);
        st[t] = __builtin_amdgcn_mfma_f32_16x16x32_bf16(kh, qf[ks], st[t], 0, 0, 0);
        bf16x8 kl = *reinterpret_cast<const bf16x8*>(
            &sC[swb(t * 16 + lr, (ks * 32 + hi4 * 8) << 1)]);
        st[t] = __builtin_amdgcn_mfma_f32_16x16x32_bf16(kl, qf[ks], st[t], 0, 0, 0);
      }
    }
    float e[4][4];
    float mx = -1e30f;
    #pragma unroll
    for (int t = 0; t < 4; ++t)
      #pragma unroll
      for (int r = 0; r < 4; ++r) { e[t][r] = st[t][r] * scale; mx = fmaxf(mx, e[t][r]); }
    mx = fmaxf(mx, __shfl_xor(mx, 16));
    mx = fmaxf(mx, __shfl_xor(mx, 32));
    float sum = 0.f;
    #pragma unroll
    for (int t = 0; t < 4; ++t)
      #pragma unroll
      for (int r = 0; r < 4; ++r) { e[t][r] = __expf(e[t][r] - mx); sum += e[t][r]; }
    sum += __shfl_xor(sum, 16);
    sum += __shfl_xor(sum, 32);
    const float inv = 1.0f / sum;
    #pragma unroll
    for (int t = 0; t < 4; ++t) {
      ushort4 p4;
      p4.x = f2bf(e[t][0] * inv); p4.y = f2bf(e[t][1] * inv);
      p4.z = f2bf(e[t][2] * inv); p4.w = f2bf(e[t][3] * inv);
      *reinterpret_cast<ushort4*>(&sP[swb(w * 16 + lr, (t * 16 + hi4 * 4) << 1)]) = p4;
    }
    #pragma unroll
    for (int ks = 0; ks < 2; ++ks) {
      bf16x8 pa = *reinterpret_cast<const bf16x8*>(
          &sP[swb(w * 16 + lr, (ks * 32 + hi4 * 8) << 1)]);
      #pragma unroll
      for (int dt = 0; dt < 4; ++dt) {
        bf16x8 vb = *reinterpret_cast<const bf16x8*>(
            &sVt[swb(dt * 16 + lr, (ks * 32 + hi4 * 8) << 1)]);
        xacc[dt] = __builtin_amdgcn_mfma_f32_16x16x32_bf16(pa, vb, xacc[dt], 0, 0, 0);
      }
    }
  }

  #pragma unroll
  for (int dt = 0; dt < 4; ++dt)
    #pragma unroll
    for (int r = 0; r < 4; ++r)
      X[tbase + (size_t)(w * 16 + hi4 * 4 + r) * DD + dt * 16 + lr] = f2bf(xacc[dt][r]);
}

// ---------------- launcher ---------------------------------------------------
extern "C" void kernel_launch(void* const* d_in, const int* in_sizes, int n_in,
                              void* d_out, int out_size, void* d_ws, size_t ws_size,
                              hipStream_t stream) {
  const float* x_in = (const float*)d_in[0];
  const float* Wq   = (const float*)d_in[1];
  const float* bq   = (const float*)d_in[2];
  const float* Wk   = (const float*)d_in[3];
  const float* bk   = (const float*)d_in[4];
  const float* Wv   = (const float*)d_in[5];
  const float* bv   = (const float*)d_in[6];
  const float* Wout = (const float*)d_in[9];
  const float* bout = (const float*)d_in[10];
  float* out = (float*)d_out;

  const size_t NTOK = (size_t)MTOT * DD;          // 8,388,608 elems
  const size_t NSUM = (size_t)BB * BS * DD;       // 131072 elems
  char* ws = (char*)d_ws;
  ushort* xb      = (ushort*)ws;            ws += NTOK * 2;
  ushort* Qb      = (ushort*)ws;            ws += NTOK * 2;
  ushort* Kb      = (ushort*)ws;            ws += NTOK * 2;
  ushort* Vb      = (ushort*)ws;            ws += NTOK * 2;
  ushort* Xb      = (ushort*)ws;            ws += NTOK * 2;
  ushort* Wqkv_t  = (ushort*)ws;            ws += (size_t)1536 * 512 * 2;
  ushort* Wout_t  = (ushort*)ws;            ws += (size_t)512 * 512 * 2;
  float*  bias_qkv= (float*)ws;             ws += 2048 * 4;
  ushort* KhiB    = (ushort*)ws;            ws += NSUM * 2;
  ushort* KloB    = (ushort*)ws;            ws += NSUM * 2;
  ushort* VsB     = (ushort*)ws;            ws += NSUM * 2;

  f32_to_bf16_vec<<<NTOK / 4 / 256, 256, 0, stream>>>(x_in, xb);
  transpose_cast4<<<dim3(16, 16, 4), 256, 0, stream>>>(
      Wq, Wk, Wv, Wout, Wqkv_t, Wout_t);
  concat_bias<<<1, 512, 0, stream>>>(bq, bk, bv, bias_qkv);

  // QKV: grid 12*128 = 1536 blocks (%8==0 for XCD swizzle)
  gemm_pipe3<0><<<12 * 128, 256, 0, stream>>>(
      xb, Wqkv_t, bias_qkv, Qb, Kb, Vb, nullptr, 1536, 12);

  sumkv_fused<<<BB * BS, 256, 0, stream>>>(Kb, Vb, KhiB, KloB, VsB);

  attn_mfma<<<dim3(NBLK, HH, BB), 256, 0, stream>>>(Qb, Kb, Vb, KhiB, KloB, VsB, Xb);

  // out: grid 4*128 = 512 blocks
  gemm_pipe3<1><<<4 * 128, 256, 0, stream>>>(
      Xb, Wout_t, bout, nullptr, nullptr, nullptr, out, 512, 4);
}

// Round 7
// 101.001 us; speedup vs baseline: 5.4303x; 1.0060x over previous
//
#include <hip/hip_runtime.h>

// SinkhornAttention — round 7: GEMM wave-tile 64x128 (block 128x256) to fix
// LDS-read-bound ratio; proper (row>>1)&3 granule swizzle (2-way = free).
// Math simplification (round 0, verified): sorted_key/value reduce to the
// block-sum of K/V; Wsort/bsort are dead.

constexpr int BB   = 4;
constexpr int LL   = 4096;
constexpr int DD   = 512;
constexpr int HH   = 8;
constexpr int HDIM = 64;
constexpr int BS   = 64;
constexpr int NBLK = 64;
constexpr int MTOT = BB * LL;   // 16384

using f32x4  = __attribute__((ext_vector_type(4))) float;
typedef __attribute__((ext_vector_type(8))) __bf16 bf16x8;

static __device__ __forceinline__ ushort f2bf(float f) {
  uint u = __float_as_uint(f);
  uint r = (u + 0x7fffu + ((u >> 16) & 1u)) >> 16;   // RNE
  return (ushort)r;
}
static __device__ __forceinline__ float bf2f(ushort u) { return __uint_as_float((uint)u << 16); }
static __device__ __forceinline__ float bflo(uint u) { return __uint_as_float(u << 16); }
static __device__ __forceinline__ float bfhi(uint u) { return __uint_as_float(u & 0xffff0000u); }

// attention-tile swizzle (64x64 bf16 tile, row stride 128 B)
static __device__ __forceinline__ int swb(int row, int cb) {
  return (row << 6) + ((cb ^ ((row & 7) << 4)) >> 1);
}

#define GLOBAL_AS(p) ((const __attribute__((address_space(1))) void*)(p))
#define LDS_AS(p)    ((__attribute__((address_space(3))) void*)(p))
#define SB0()        __builtin_amdgcn_sched_barrier(0)

// ---------------- f32 -> bf16 straight cast (4 elems/thread) -----------------
__global__ __launch_bounds__(256) void f32_to_bf16_vec(
    const float* __restrict__ src, ushort* __restrict__ dst)
{
  const int i = blockIdx.x * 256 + threadIdx.x;
  float4 v = reinterpret_cast<const float4*>(src)[i];
  ushort4 o;
  o.x = f2bf(v.x); o.y = f2bf(v.y); o.z = f2bf(v.z); o.w = f2bf(v.w);
  reinterpret_cast<ushort4*>(dst)[i] = o;
}

// ------------- 4x transpose + cast (one launch): f32 [512][512] -> bf16^T ----
__global__ __launch_bounds__(256) void transpose_cast4(
    const float* __restrict__ Wq, const float* __restrict__ Wk,
    const float* __restrict__ Wv, const float* __restrict__ Wo,
    ushort* __restrict__ Wqkv_t, ushort* __restrict__ Wout_t)
{
  __shared__ float tile[32][33];
  const int z  = blockIdx.z;
  const float* src = (z == 0) ? Wq : (z == 1) ? Wk : (z == 2) ? Wv : Wo;
  ushort* dst = (z < 3) ? (Wqkv_t + (size_t)z * 512 * 512) : Wout_t;
  const int tx = threadIdx.x & 31, ty = threadIdx.x >> 5;   // 32 x 8
  const int r0 = blockIdx.y * 32, c0 = blockIdx.x * 32;
  #pragma unroll
  for (int q = 0; q < 4; ++q)
    tile[ty + 8 * q][tx] = src[(size_t)(r0 + ty + 8 * q) * 512 + c0 + tx];
  __syncthreads();
  #pragma unroll
  for (int q = 0; q < 4; ++q)
    dst[(size_t)(c0 + ty + 8 * q) * 512 + r0 + tx] = f2bf(tile[tx][ty + 8 * q]);
}

// ---------------- concat Q/K/V biases into one f32[1536] ---------------------
__global__ void concat_bias(const float* __restrict__ bq, const float* __restrict__ bk,
                            const float* __restrict__ bv, float* __restrict__ o)
{
  const int t = threadIdx.x;   // 512
  o[t] = bq[t]; o[512 + t] = bk[t]; o[1024 + t] = bv[t];
}

// ---------------- pipelined MFMA GEMM: C[M,N] = A[M,512] @ Bt[N,512]^T + b ---
// Block tile 128 x TN (TN=256 or 128), BK=32, 4 waves (2x2), per-wave output
// 64 x TN/2. 3-deep LDS pipeline (stage t+2 while computing t), counted vmcnt
// gates (never 0 in steady state), 1 raw barrier per K-step, (row>>1)&3
// granule swizzle -> 2-way (free) ds_read_b128 conflicts.
// MODE 0: scatter bf16 into Q/K/V (col>>9 selects). MODE 1: f32 out.
template<int MODE, int TN>
__global__ __launch_bounds__(256, 2) void gemm_pipe3(
    const ushort* __restrict__ A, const ushort* __restrict__ Bt,
    const float* __restrict__ bias,
    ushort* __restrict__ Cq, ushort* __restrict__ Ck, ushort* __restrict__ Cv,
    float* __restrict__ Cf, int N, int NBX)
{
  constexpr int K   = 512;
  constexpr int NT  = K / 32;         // 16 K-steps
  constexpr int NF  = TN / 32;        // B-frags per wave (8 or 4)
  constexpr int BCH = TN / 64;        // B stage chunks per K-step (4 or 2)
  __shared__ __align__(16) ushort sA[3][128 * 32];
  __shared__ __align__(16) ushort sB[3][TN * 32];

  const int tid  = threadIdx.x;
  const int lane = tid & 63;
  const int w    = tid >> 6;
  const int wr   = w >> 1, wc = w & 1;
  const int lr   = lane & 15;
  const int kq   = lane >> 4;

  // XCD-chunked block swizzle (grid % 8 == 0), nb fastest within a chunk
  const int nwg  = NBX * 128;
  const int cpx  = nwg >> 3;
  const int swz  = ((int)blockIdx.x & 7) * cpx + ((int)blockIdx.x >> 3);
  const int nb   = swz % NBX;
  const int mb   = swz / NBX;
  const int brow = mb * 128;
  const int bcol = nb * TN;

  // stage chunk j: 256 thr x 16 B; LDS linear, source granule pre-swizzled
  // (g ^= (row>>1)&3) so fragment reads de-bank to 2-way (free).
  auto stageA = [&](int buf, int t, int j) {
    const int c   = j * 256 + tid;
    const int row = c >> 2, ch = c & 3;
    const ushort* src = A + (size_t)(brow + row) * K + t * 32 + ((ch ^ ((row >> 1) & 3)) << 3);
    __builtin_amdgcn_global_load_lds(GLOBAL_AS(src),
        LDS_AS(&sA[buf][(j * 256 + (w << 6)) << 3]), 16, 0, 0);
  };
  auto stageB = [&](int buf, int t, int j) {
    const int c   = j * 256 + tid;
    const int row = c >> 2, ch = c & 3;
    const ushort* src = Bt + (size_t)(bcol + row) * K + t * 32 + ((ch ^ ((row >> 1) & 3)) << 3);
    __builtin_amdgcn_global_load_lds(GLOBAL_AS(src),
        LDS_AS(&sB[buf][(j * 256 + (w << 6)) << 3]), 16, 0, 0);
  };
  auto ldA = [&](int buf, int mf) -> bf16x8 {
    const int row = (wr << 6) + (mf << 4) + lr;
    return *reinterpret_cast<const bf16x8*>(&sA[buf][(row << 5) + ((kq ^ ((row >> 1) & 3)) << 3)]);
  };
  auto ldB = [&](int buf, int nf) -> bf16x8 {
    const int row = wc * (TN >> 1) + (nf << 4) + lr;
    return *reinterpret_cast<const bf16x8*>(&sB[buf][(row << 5) + ((kq ^ ((row >> 1) & 3)) << 3)]);
  };
  auto stageAll = [&](int buf, int t) {
    stageA(buf, t, 0); stageA(buf, t, 1);
    #pragma unroll
    for (int j = 0; j < BCH; ++j) stageB(buf, t, j);
  };
  auto gate = [&]() {   // keep next-next tile's (2+BCH) loads in flight
    if constexpr (BCH == 4) asm volatile("s_waitcnt vmcnt(6)" ::: "memory");
    else                    asm volatile("s_waitcnt vmcnt(4)" ::: "memory");
  };

  f32x4 acc[4][NF];
  #pragma unroll
  for (int mi = 0; mi < 4; ++mi)
    #pragma unroll
    for (int ni = 0; ni < NF; ++ni)
      acc[mi][ni] = (f32x4){0.f, 0.f, 0.f, 0.f};

  // ---- prologue: stage K-steps 0 and 1
  stageAll(0, 0);
  stageAll(1, 1);
  gate();
  SB0(); __builtin_amdgcn_s_barrier(); SB0();

  for (int t = 0; t < NT; ++t) {
    const int buf  = t % 3;
    const int nbuf = (t + 2) % 3;
    const bool more = (t + 2) < NT;

    bf16x8 af[4], bfr[NF];
    #pragma unroll
    for (int mf = 0; mf < 4; ++mf) af[mf] = ldA(buf, mf);
    #pragma unroll
    for (int nf = 0; nf < NF; ++nf) bfr[nf] = ldB(buf, nf);
    if (more) stageAll(nbuf, t + 2);
    SB0();
    __builtin_amdgcn_s_setprio(1);
    #pragma unroll
    for (int mi = 0; mi < 4; ++mi)
      #pragma unroll
      for (int ni = 0; ni < NF; ++ni)
        acc[mi][ni] = __builtin_amdgcn_mfma_f32_16x16x32_bf16(af[mi], bfr[ni], acc[mi][ni], 0, 0, 0);
    __builtin_amdgcn_s_setprio(0);
    SB0();
    if (more) gate();
    else      asm volatile("s_waitcnt vmcnt(0)" ::: "memory");
    SB0(); __builtin_amdgcn_s_barrier(); SB0();
  }

  // ---- epilogue: bias + store (C/D layout: col=lane&15, row=(lane>>4)*4+r)
  #pragma unroll
  for (int mi = 0; mi < 4; ++mi) {
    #pragma unroll
    for (int ni = 0; ni < NF; ++ni) {
      const int col = bcol + wc * (TN >> 1) + ni * 16 + lr;
      const float bb = bias[col];
      if (MODE == 0) {
        const int which = col >> 9;
        const int nn    = col & 511;
        ushort* dst = (which == 0) ? Cq : ((which == 1) ? Ck : Cv);
        #pragma unroll
        for (int r = 0; r < 4; ++r) {
          const int row = brow + wr * 64 + mi * 16 + kq * 4 + r;
          dst[(size_t)row * DD + nn] = f2bf(acc[mi][ni][r] + bb);
        }
      } else {
        #pragma unroll
        for (int r = 0; r < 4; ++r) {
          const int row = brow + wr * 64 + mi * 16 + kq * 4 + r;
          Cf[(size_t)row * N + col] = acc[mi][ni][r] + bb;
        }
      }
    }
  }
}

// ---------------- fused block-sum of K,V -> Khi/Klo/Vb (no atomics) ----------
__global__ __launch_bounds__(256) void sumkv_fused(
    const ushort* __restrict__ K, const ushort* __restrict__ V,
    ushort* __restrict__ Khi, ushort* __restrict__ Klo, ushort* __restrict__ Vb)
{
  __shared__ float kbuf[4][64][9];
  __shared__ float vbuf[4][64][9];
  const int bs   = blockIdx.x;          // b*64 + s
  const int b    = bs >> 6, s = bs & 63;
  const int lane = threadIdx.x & 63;
  const int kbq  = threadIdx.x >> 6;
  const size_t rowbase = ((size_t)b * LL + s) * DD + lane * 8;

  float ak[8] = {0,0,0,0,0,0,0,0}, av[8] = {0,0,0,0,0,0,0,0};
  #pragma unroll
  for (int i = 0; i < 16; ++i) {
    const size_t off = rowbase + (size_t)(kbq * 16 + i) * BS * DD;
    uint4 ku = *reinterpret_cast<const uint4*>(K + off);
    uint4 vu = *reinterpret_cast<const uint4*>(V + off);
    ak[0] += bflo(ku.x); ak[1] += bfhi(ku.x); ak[2] += bflo(ku.y); ak[3] += bfhi(ku.y);
    ak[4] += bflo(ku.z); ak[5] += bfhi(ku.z); ak[6] += bflo(ku.w); ak[7] += bfhi(ku.w);
    av[0] += bflo(vu.x); av[1] += bfhi(vu.x); av[2] += bflo(vu.y); av[3] += bfhi(vu.y);
    av[4] += bflo(vu.z); av[5] += bfhi(vu.z); av[6] += bflo(vu.w); av[7] += bfhi(vu.w);
  }
  #pragma unroll
  for (int j = 0; j < 8; ++j) { kbuf[kbq][lane][j] = ak[j]; vbuf[kbq][lane][j] = av[j]; }
  __syncthreads();

  const size_t wbase = (size_t)bs * DD + lane * 8;
  if (kbq == 0) {
    uint4 hi4, lo4;
    uint* hp = reinterpret_cast<uint*>(&hi4);
    uint* lp = reinterpret_cast<uint*>(&lo4);
    #pragma unroll
    for (int p = 0; p < 4; ++p) {
      uint hw = 0, lw = 0;
      #pragma unroll
      for (int q = 0; q < 2; ++q) {
        const int j = p * 2 + q;
        const float t = kbuf[0][lane][j] + kbuf[1][lane][j] +
                        kbuf[2][lane][j] + kbuf[3][lane][j];
        const ushort h = f2bf(t);
        const ushort l = f2bf(t - bf2f(h));
        hw |= (uint)h << (16 * q);
        lw |= (uint)l << (16 * q);
      }
      hp[p] = hw; lp[p] = lw;
    }
    *reinterpret_cast<uint4*>(Khi + wbase) = hi4;
    *reinterpret_cast<uint4*>(Klo + wbase) = lo4;
  } else if (kbq == 1) {
    uint4 o4;
    uint* op = reinterpret_cast<uint*>(&o4);
    #pragma unroll
    for (int p = 0; p < 4; ++p) {
      uint wv = 0;
      #pragma unroll
      for (int q = 0; q < 2; ++q) {
        const int j = p * 2 + q;
        const float t = vbuf[0][lane][j] + vbuf[1][lane][j] +
                        vbuf[2][lane][j] + vbuf[3][lane][j];
        wv |= (uint)f2bf(t) << (16 * q);
      }
      op[p] = wv;
    }
    *reinterpret_cast<uint4*>(Vb + wbase) = o4;
  }
}

// ---------------- MFMA two-pass block attention ------------------------------
__global__ __launch_bounds__(256) void attn_mfma(
    const ushort* __restrict__ Q, const ushort* __restrict__ Kg,
    const ushort* __restrict__ Vg, const ushort* __restrict__ Khi,
    const ushort* __restrict__ Klo, const ushort* __restrict__ Vsb,
    ushort* __restrict__ X)
{
  __shared__ __align__(16) ushort sA[64 * 64];   // K, then Khi
  __shared__ __align__(16) ushort sC[64 * 64];   // Klo (pass 2)
  __shared__ __align__(16) ushort sVt[64 * 64];  // V^T, then Vsum^T
  __shared__ __align__(16) ushort sP[64 * 64];   // P (per-wave 16-row slices)
  const int n = blockIdx.x, h = blockIdx.y, b = blockIdx.z;
  const int tid  = threadIdx.x;
  const int lane = tid & 63;
  const int w    = tid >> 6;
  const int lr   = lane & 15, hi4 = lane >> 4;
  const float scale = 0.125f;

  const size_t tbase = ((size_t)(b * LL + n * BS)) * DD + h * HDIM;
  const size_t sbase = ((size_t)(b * BS)) * DD + h * HDIM;

  uint4 k1[2], v1[2], k2h[2], k2l[2], v2[2];
  int rr[2], cc[2];
  #pragma unroll
  for (int it = 0; it < 2; ++it) {
    const int i  = tid + it * 256;      // 0..511
    const int r  = i >> 3;
    const int c8 = (i & 7) << 3;
    rr[it] = r; cc[it] = c8;
    const size_t g1 = tbase + (size_t)r * DD + c8;
    const size_t g2 = sbase + (size_t)r * DD + c8;
    k1[it]  = *reinterpret_cast<const uint4*>(Kg  + g1);
    v1[it]  = *reinterpret_cast<const uint4*>(Vg  + g1);
    k2h[it] = *reinterpret_cast<const uint4*>(Khi + g2);
    k2l[it] = *reinterpret_cast<const uint4*>(Klo + g2);
    v2[it]  = *reinterpret_cast<const uint4*>(Vsb + g2);
  }
  bf16x8 qf[2];
  #pragma unroll
  for (int ks = 0; ks < 2; ++ks)
    qf[ks] = *reinterpret_cast<const bf16x8*>(
        Q + tbase + (size_t)(w * 16 + lr) * DD + ks * 32 + hi4 * 8);

  #pragma unroll
  for (int it = 0; it < 2; ++it) {
    *reinterpret_cast<uint4*>(&sA[swb(rr[it], cc[it] << 1)]) = k1[it];
    const uint u[4] = {v1[it].x, v1[it].y, v1[it].z, v1[it].w};
    #pragma unroll
    for (int j = 0; j < 4; ++j) {
      sVt[swb(cc[it] + 2 * j,     rr[it] << 1)] = (ushort)(u[j] & 0xffff);
      sVt[swb(cc[it] + 2 * j + 1, rr[it] << 1)] = (ushort)(u[j] >> 16);
    }
  }
  __syncthreads();

  f32x4 xacc[4];
  #pragma unroll
  for (int dt = 0; dt < 4; ++dt) xacc[dt] = (f32x4){0.f, 0.f, 0.f, 0.f};

  // ================= PASS 1 =================
  {
    f32x4 st[4];
    #pragma unroll
    for (int t = 0; t < 4; ++t) st[t] = (f32x4){0.f, 0.f, 0.f, 0.f};
    #pragma unroll
    for (int ks = 0; ks < 2; ++ks) {
      #pragma unroll
      for (int t = 0; t < 4; ++t) {
        bf16x8 kf = *reinterpret_cast<const bf16x8*>(
            &sA[swb(t * 16 + lr, (ks * 32 + hi4 * 8) << 1)]);
        st[t] = __builtin_amdgcn_mfma_f32_16x16x32_bf16(kf, qf[ks], st[t], 0, 0, 0);
      }
    }
    float e[4][4];
    float mx = -1e30f;
    #pragma unroll
    for (int t = 0; t < 4; ++t)
      #pragma unroll
      for (int r = 0; r < 4; ++r) { e[t][r] = st[t][r] * scale; mx = fmaxf(mx, e[t][r]); }
    mx = fmaxf(mx, __shfl_xor(mx, 16));
    mx = fmaxf(mx, __shfl_xor(mx, 32));
    float sum = 0.f;
    #pragma unroll
    for (int t = 0; t < 4; ++t)
      #pragma unroll
      for (int r = 0; r < 4; ++r) { e[t][r] = __expf(e[t][r] - mx); sum += e[t][r]; }
    sum += __shfl_xor(sum, 16);
    sum += __shfl_xor(sum, 32);
    const float inv = 1.0f / sum;
    #pragma unroll
    for (int t = 0; t < 4; ++t) {
      ushort4 p4;
      p4.x = f2bf(e[t][0] * inv); p4.y = f2bf(e[t][1] * inv);
      p4.z = f2bf(e[t][2] * inv); p4.w = f2bf(e[t][3] * inv);
      *reinterpret_cast<ushort4*>(&sP[swb(w * 16 + lr, (t * 16 + hi4 * 4) << 1)]) = p4;
    }
    #pragma unroll
    for (int ks = 0; ks < 2; ++ks) {
      bf16x8 pa = *reinterpret_cast<const bf16x8*>(
          &sP[swb(w * 16 + lr, (ks * 32 + hi4 * 8) << 1)]);
      #pragma unroll
      for (int dt = 0; dt < 4; ++dt) {
        bf16x8 vb = *reinterpret_cast<const bf16x8*>(
            &sVt[swb(dt * 16 + lr, (ks * 32 + hi4 * 8) << 1)]);
        xacc[dt] = __builtin_amdgcn_mfma_f32_16x16x32_bf16(pa, vb, xacc[dt], 0, 0, 0);
      }
    }
  }
  __syncthreads();

  #pragma unroll
  for (int it = 0; it < 2; ++it) {
    *reinterpret_cast<uint4*>(&sA[swb(rr[it], cc[it] << 1)]) = k2h[it];
    *reinterpret_cast<uint4*>(&sC[swb(rr[it], cc[it] << 1)]) = k2l[it];
    const uint u[4] = {v2[it].x, v2[it].y, v2[it].z, v2[it].w};
    #pragma unroll
    for (int j = 0; j < 4; ++j) {
      sVt[swb(cc[it] + 2 * j,     rr[it] << 1)] = (ushort)(u[j] & 0xffff);
      sVt[swb(cc[it] + 2 * j + 1, rr[it] << 1)] = (ushort)(u[j] >> 16);
    }
  }
  __syncthreads();

  // ================= PASS 2 =================
  {
    f32x4 st[4];
    #pragma unroll
    for (int t = 0; t < 4; ++t) st[t] = (f32x4){0.f, 0.f, 0.f, 0.f};
    #pragma unroll
    for (int ks = 0; ks < 2; ++ks) {
      #pragma unroll
      for (int t = 0; t < 4; ++t) {
        bf16x8 kh = *reinterpret_cast<const bf16x8*>(
            &sA[swb(t * 16 + lr, (ks * 32 + hi4 * 8) << 1)]);
        st[t] = __builtin_amdgcn_mfma_f32_16x16x32_bf16(kh, qf[ks], st[t], 0, 0, 0);
        bf16x8 kl = *reinterpret_cast<const bf16x8*>(
            &sC[swb(t * 16 + lr, (ks * 32 + hi4 * 8) << 1)]);
        st[t] = __builtin_amdgcn_mfma_f32_16x16x32_bf16(kl, qf[ks], st[t], 0, 0, 0);
      }
    }
    float e[4][4];
    float mx = -1e30f;
    #pragma unroll
    for (int t = 0; t < 4; ++t)
      #pragma unroll
      for (int r = 0; r < 4; ++r) { e[t][r] = st[t][r] * scale; mx = fmaxf(mx, e[t][r]); }
    mx = fmaxf(mx, __shfl_xor(mx, 16));
    mx = fmaxf(mx, __shfl_xor(mx, 32));
    float sum = 0.f;
    #pragma unroll
    for (int t = 0; t < 4; ++t)
      #pragma unroll
      for (int r = 0; r < 4; ++r) { e[t][r] = __expf(e[t][r] - mx); sum += e[t][r]; }
    sum += __shfl_xor(sum, 16);
    sum += __shfl_xor(sum, 32);
    const float inv = 1.0f / sum;
    #pragma unroll
    for (int t = 0; t < 4; ++t) {
      ushort4 p4;
      p4.x = f2bf(e[t][0] * inv); p4.y = f2bf(e[t][1] * inv);
      p4.z = f2bf(e[t][2] * inv); p4.w = f2bf(e[t][3] * inv);
      *reinterpret_cast<ushort4*>(&sP[swb(w * 16 + lr, (t * 16 + hi4 * 4) << 1)]) = p4;
    }
    #pragma unroll
    for (int ks = 0; ks < 2; ++ks) {
      bf16x8 pa = *reinterpret_cast<const bf16x8*>(
          &sP[swb(w * 16 + lr, (ks * 32 + hi4 * 8) << 1)]);
      #pragma unroll
      for (int dt = 0; dt < 4; ++dt) {
        bf16x8 vb = *reinterpret_cast<const bf16x8*>(
            &sVt[swb(dt * 16 + lr, (ks * 32 + hi4 * 8) << 1)]);
        xacc[dt] = __builtin_amdgcn_mfma_f32_16x16x32_bf16(pa, vb, xacc[dt], 0, 0, 0);
      }
    }
  }

  #pragma unroll
  for (int dt = 0; dt < 4; ++dt)
    #pragma unroll
    for (int r = 0; r < 4; ++r)
      X[tbase + (size_t)(w * 16 + hi4 * 4 + r) * DD + dt * 16 + lr] = f2bf(xacc[dt][r]);
}

// ---------------- launcher ---------------------------------------------------
extern "C" void kernel_launch(void* const* d_in, const int* in_sizes, int n_in,
                              void* d_out, int out_size, void* d_ws, size_t ws_size,
                              hipStream_t stream) {
  const float* x_in = (const float*)d_in[0];
  const float* Wq   = (const float*)d_in[1];
  const float* bq   = (const float*)d_in[2];
  const float* Wk   = (const float*)d_in[3];
  const float* bk   = (const float*)d_in[4];
  const float* Wv   = (const float*)d_in[5];
  const float* bv   = (const float*)d_in[6];
  const float* Wout = (const float*)d_in[9];
  const float* bout = (const float*)d_in[10];
  float* out = (float*)d_out;

  const size_t NTOK = (size_t)MTOT * DD;          // 8,388,608 elems
  const size_t NSUM = (size_t)BB * BS * DD;       // 131072 elems
  char* ws = (char*)d_ws;
  ushort* xb      = (ushort*)ws;            ws += NTOK * 2;
  ushort* Qb      = (ushort*)ws;            ws += NTOK * 2;
  ushort* Kb      = (ushort*)ws;            ws += NTOK * 2;
  ushort* Vb      = (ushort*)ws;            ws += NTOK * 2;
  ushort* Xb      = (ushort*)ws;            ws += NTOK * 2;
  ushort* Wqkv_t  = (ushort*)ws;            ws += (size_t)1536 * 512 * 2;
  ushort* Wout_t  = (ushort*)ws;            ws += (size_t)512 * 512 * 2;
  float*  bias_qkv= (float*)ws;             ws += 2048 * 4;
  ushort* KhiB    = (ushort*)ws;            ws += NSUM * 2;
  ushort* KloB    = (ushort*)ws;            ws += NSUM * 2;
  ushort* VsB     = (ushort*)ws;            ws += NSUM * 2;

  f32_to_bf16_vec<<<NTOK / 4 / 256, 256, 0, stream>>>(x_in, xb);
  transpose_cast4<<<dim3(16, 16, 4), 256, 0, stream>>>(
      Wq, Wk, Wv, Wout, Wqkv_t, Wout_t);
  concat_bias<<<1, 512, 0, stream>>>(bq, bk, bv, bias_qkv);

  // QKV: tile 128x256, grid 6*128 = 768 blocks (%8==0 for XCD swizzle)
  gemm_pipe3<0, 256><<<6 * 128, 256, 0, stream>>>(
      xb, Wqkv_t, bias_qkv, Qb, Kb, Vb, nullptr, 1536, 6);

  sumkv_fused<<<BB * BS, 256, 0, stream>>>(Kb, Vb, KhiB, KloB, VsB);

  attn_mfma<<<dim3(NBLK, HH, BB), 256, 0, stream>>>(Qb, Kb, Vb, KhiB, KloB, VsB, Xb);

  // out: tile 128x128, grid 4*128 = 512 blocks
  gemm_pipe3<1, 128><<<4 * 128, 256, 0, stream>>>(
      Xb, Wout_t, bout, nullptr, nullptr, nullptr, out, 512, 4);
}